// Round 1
// 311.392 us; speedup vs baseline: 1.0324x; 1.0324x over previous
//
#include <hip/hip_runtime.h>

#define NN 50000
#define EE 800000
#define D  128
#define SBLK 49        // ceil(NN/1024) for scan
#define ZRB 245        // zero blocks: 62500 float4 / 256
#define PKB 384        // pack blocks: 6*16384/256
#define DRB 391        // degrank blocks: 391*2048 >= EE (8 edges/thread)
#define XHB 782        // xh blocks: ceil(NN/64)

typedef short short8 __attribute__((ext_vector_type(8)));
typedef float floatx4 __attribute__((ext_vector_type(4)));

__device__ __forceinline__ float leaky(float v) { return v > 0.f ? v : 0.01f * v; }

__device__ __forceinline__ unsigned short f2bf(float f) {
    unsigned int u = __float_as_uint(f);
    u = (u + 0x7fff + ((u >> 16) & 1)) >> 16;     // round-to-nearest-even
    return (unsigned short)u;
}
__device__ __forceinline__ float bf2f(unsigned int h) {
    return __uint_as_float(h << 16);
}

// ------------- phase A: zero(deg4+cntI) ∥ pack weights (independent halves) -------------
__global__ __launch_bounds__(256) void k_pre(
    float4* __restrict__ zp,                 // deg4+cntI region, 62500 float4
    const float* __restrict__ Wp,  const float* __restrict__ Wc0,
    const float* __restrict__ Wc1, const float* __restrict__ Wrel,
    const float* __restrict__ Wroot, const float* __restrict__ Wl,
    unsigned short* __restrict__ Pall) {
    int b = blockIdx.x;
    if (b < ZRB) {
        int i = b * 256 + threadIdx.x;
        if (i < 62500) zp[i] = make_float4(0.f, 0.f, 0.f, 0.f);
    } else {
        int gid = (b - ZRB) * 256 + threadIdx.x;
        int mm = gid >> 14;
        int r = gid & 16383;
        int j  = r & 7;
        int l  = (r >> 3) & 63;
        int ct = (r >> 9) & 7;
        int kc = r >> 12;
        int n = ct * 16 + (l & 15);
        int k = kc * 32 + (l >> 4) * 8 + j;
        const float* W = mm == 0 ? Wp : mm == 1 ? Wc0 : mm == 2 ? Wc1
                       : mm == 3 ? Wrel : mm == 4 ? Wroot : Wl;
        Pall[gid] = f2bf(W[n * 128 + k]);
    }
}

// ------------- phase B: degrank (8 edges/thread, batched atomics) ∥ xh(+his copy) -------------
__global__ __launch_bounds__(256) void k_front(
    const int* __restrict__ src, const int* __restrict__ dst,
    const float* __restrict__ ew, float* __restrict__ deg4,
    int* __restrict__ cntI, int* __restrict__ rank,
    const float* __restrict__ x, const float* __restrict__ bp,
    unsigned short* __restrict__ xh16, float* __restrict__ his,
    const unsigned short* __restrict__ Pall) {
    int b = blockIdx.x;
    if (b < DRB) {
        // ---- degrank: deg4[j&3][src]+=w ; rank[e] = cnt[dst]++ ----
        // 8 edges/thread: vectorized loads, 16 atomics in flight before one wait.
        int t = b * 2048 + threadIdx.x * 8;
        if (t < EE) {                       // EE % 8 == 0 → all 8 in-bounds
            int4   s0 = *(const int4*)(src + t);
            int4   s1 = *(const int4*)(src + t + 4);
            int4   d0 = *(const int4*)(dst + t);
            int4   d1 = *(const int4*)(dst + t + 4);
            float4 w0 = *(const float4*)(ew + t);
            float4 w1 = *(const float4*)(ew + t + 4);
            // fire-and-forget weighted-degree shards (no return → no wait)
            atomicAdd(&deg4[0 * NN + s0.x], w0.x);
            atomicAdd(&deg4[1 * NN + s0.y], w0.y);
            atomicAdd(&deg4[2 * NN + s0.z], w0.z);
            atomicAdd(&deg4[3 * NN + s0.w], w0.w);
            atomicAdd(&deg4[0 * NN + s1.x], w1.x);
            atomicAdd(&deg4[1 * NN + s1.y], w1.y);
            atomicAdd(&deg4[2 * NN + s1.z], w1.z);
            atomicAdd(&deg4[3 * NN + s1.w], w1.w);
            // with-return rank atomics: 8 outstanding round trips per thread
            int r0 = atomicAdd(&cntI[d0.x], 1);
            int r1 = atomicAdd(&cntI[d0.y], 1);
            int r2 = atomicAdd(&cntI[d0.z], 1);
            int r3 = atomicAdd(&cntI[d0.w], 1);
            int r4 = atomicAdd(&cntI[d1.x], 1);
            int r5 = atomicAdd(&cntI[d1.y], 1);
            int r6 = atomicAdd(&cntI[d1.z], 1);
            int r7 = atomicAdd(&cntI[d1.w], 1);
            *(int4*)(rank + t)     = make_int4(r0, r1, r2, r3);
            *(int4*)(rank + t + 4) = make_int4(r4, r5, r6, r7);
        }
    } else {
        // ---- xh = x @ Wp^T + bp (bf16 MFMA) + his = x copy ----
        int bb = b - DRB;
        const unsigned short* Pp = Pall;   // slot 0
        int wave = threadIdx.x >> 6, l = threadIdx.x & 63;
        int n0 = bb * 64 + wave * 16;
        int m = l & 15, q = l >> 4;
        int nodeA = n0 + m;
        bool av = nodeA < NN;
        int na = av ? nodeA : 0;
        floatx4 acc[8];
#pragma unroll
        for (int ct = 0; ct < 8; ++ct) acc[ct] = (floatx4)(0.f);
#pragma unroll
        for (int kc = 0; kc < 4; ++kc) {
            const float* ap = x + (size_t)na * 128 + kc * 32 + q * 8;
            float4 f0 = av ? *(const float4*)ap       : make_float4(0, 0, 0, 0);
            float4 f1 = av ? *(const float4*)(ap + 4) : make_float4(0, 0, 0, 0);
            if (av) {
                float* hp = his + (size_t)nodeA * 128 + kc * 32 + q * 8;
                *(float4*)hp       = f0;
                *(float4*)(hp + 4) = f1;
            }
            short8 a;
            a[0] = f2bf(f0.x); a[1] = f2bf(f0.y); a[2] = f2bf(f0.z); a[3] = f2bf(f0.w);
            a[4] = f2bf(f1.x); a[5] = f2bf(f1.y); a[6] = f2bf(f1.z); a[7] = f2bf(f1.w);
#pragma unroll
            for (int ct = 0; ct < 8; ++ct) {
                short8 bfr = *(const short8*)(Pp + ((kc * 8 + ct) << 9) + l * 8);
                acc[ct] = __builtin_amdgcn_mfma_f32_16x16x32_bf16(a, bfr, acc[ct], 0, 0, 0);
            }
        }
#pragma unroll
        for (int ct = 0; ct < 8; ++ct) {
            int col = ct * 16 + m;
            float bias = bp[col];
#pragma unroll
            for (int r = 0; r < 4; ++r) {
                int node = n0 + q * 4 + r;
                if (node < NN) xh16[(size_t)node * 128 + col] = f2bf(acc[ct][r] + bias);
            }
        }
    }
}

// ------------- scan phase 1 + deg4 reduce -> deg -------------
__global__ __launch_bounds__(256) void k_scan_part(const int* __restrict__ cntI,
                                                   const float* __restrict__ deg4,
                                                   int* __restrict__ blocksum,
                                                   float* __restrict__ deg) {
    __shared__ int wsum[4];
    int t = threadIdx.x;
    int base = blockIdx.x * 1024 + t * 4;
    int s = 0;
#pragma unroll
    for (int j = 0; j < 4; ++j) {
        int i = base + j;
        if (i < NN) {
            s += cntI[i];
            deg[i] = deg4[i] + deg4[NN + i] + deg4[2 * NN + i] + deg4[3 * NN + i];
        }
    }
#pragma unroll
    for (int off = 32; off > 0; off >>= 1) s += __shfl_down(s, off, 64);
    if ((t & 63) == 0) wsum[t >> 6] = s;
    __syncthreads();
    if (t == 0) blocksum[blockIdx.x] = wsum[0] + wsum[1] + wsum[2] + wsum[3];
}

__global__ __launch_bounds__(64) void k_scan_mid(const int* __restrict__ blocksum,
                                                 int* __restrict__ blockoff,
                                                 int* __restrict__ rowstart) {
    int t = threadIdx.x;
    int v = (t < SBLK) ? blocksum[t] : 0;
    int incl = v;
#pragma unroll
    for (int off = 1; off < 64; off <<= 1) {
        int u = __shfl_up(incl, off, 64);
        if (t >= off) incl += u;
    }
    if (t < SBLK) blockoff[t] = incl - v;
    if (t == 63) rowstart[NN] = incl;
}

__global__ __launch_bounds__(256) void k_scan_final(const int* __restrict__ cntI,
                                                    const int* __restrict__ blockoff,
                                                    int* __restrict__ rowstart) {
    __shared__ int wtot[4];
    int t = threadIdx.x, lane = t & 63, wave = t >> 6;
    int base = blockIdx.x * 1024 + t * 4;
    int v[4]; int s = 0;
#pragma unroll
    for (int j = 0; j < 4; ++j) { int i = base + j; v[j] = (i < NN) ? cntI[i] : 0; s += v[j]; }
    int incl = s;
#pragma unroll
    for (int off = 1; off < 64; off <<= 1) {
        int u = __shfl_up(incl, off, 64);
        if (lane >= off) incl += u;
    }
    if (lane == 63) wtot[wave] = incl;
    __syncthreads();
    int wpre = 0;
    for (int wv = 0; wv < wave; ++wv) wpre += wtot[wv];
    int run = blockoff[blockIdx.x] + wpre + (incl - s);
#pragma unroll
    for (int j = 0; j < 4; ++j) {
        int i = base + j;
        if (i < NN) rowstart[i] = run;
        run += v[j];
    }
}

// ------------- bucket edges by dst, NO atomics: rec[pos] = {src, w, dis_s*w, 0} -------------
__global__ void k_bucket(const int* __restrict__ src, const int* __restrict__ dst,
                         const float* __restrict__ ew, const float* __restrict__ deg,
                         const int* __restrict__ rowstart, const int* __restrict__ rank,
                         int4* __restrict__ rec) {
    int e = blockIdx.x * blockDim.x + threadIdx.x;
    if (e >= EE) return;
    int s = src[e], d = dst[e];
    float w = ew[e];
    float degs = deg[s];
    float dis_s = degs > 0.f ? rsqrtf(degs) : 0.f;
    int pos = rowstart[d] + rank[e];
    int4 r;
    r.x = s;
    r.y = __float_as_int(w);
    r.z = __float_as_int(dis_s * w);
    r.w = 0;
    rec[pos] = r;
}

// ------------- per-dst gather on bf16 xh: Tx1, mean → bf16 -------------
__global__ __launch_bounds__(256) void k_gather(const int* __restrict__ rowstart,
                                                const int4* __restrict__ rec,
                                                const float* __restrict__ deg,
                                                const unsigned short* __restrict__ xh16,
                                                unsigned int* __restrict__ tx16,
                                                unsigned int* __restrict__ mn16) {
    int wave = threadIdx.x >> 6, l = threadIdx.x & 63;
    int n = blockIdx.x * 4 + wave;
    if (n >= NN) return;
    int lo = rowstart[n], hi = rowstart[n + 1];
    float at0 = 0.f, at1 = 0.f, am0 = 0.f, am1 = 0.f;
    int e = lo;
    for (; e + 3 < hi; e += 4) {
        int4 r0 = rec[e], r1 = rec[e + 1], r2 = rec[e + 2], r3 = rec[e + 3];
        unsigned int v0 = *(const unsigned int*)(xh16 + (size_t)r0.x * 128 + l * 2);
        unsigned int v1 = *(const unsigned int*)(xh16 + (size_t)r1.x * 128 + l * 2);
        unsigned int v2 = *(const unsigned int*)(xh16 + (size_t)r2.x * 128 + l * 2);
        unsigned int v3 = *(const unsigned int*)(xh16 + (size_t)r3.x * 128 + l * 2);
        float w0 = __int_as_float(r0.y), u0 = __int_as_float(r0.z);
        float w1 = __int_as_float(r1.y), u1 = __int_as_float(r1.z);
        float w2 = __int_as_float(r2.y), u2 = __int_as_float(r2.z);
        float w3 = __int_as_float(r3.y), u3 = __int_as_float(r3.z);
        float a0 = bf2f(v0 & 0xffff), a1 = bf2f(v0 >> 16);
        float b0 = bf2f(v1 & 0xffff), b1 = bf2f(v1 >> 16);
        float c0 = bf2f(v2 & 0xffff), c1 = bf2f(v2 >> 16);
        float d0 = bf2f(v3 & 0xffff), d1 = bf2f(v3 >> 16);
        am0 = fmaf(w0, a0, am0); am1 = fmaf(w0, a1, am1);
        at0 = fmaf(u0, a0, at0); at1 = fmaf(u0, a1, at1);
        am0 = fmaf(w1, b0, am0); am1 = fmaf(w1, b1, am1);
        at0 = fmaf(u1, b0, at0); at1 = fmaf(u1, b1, at1);
        am0 = fmaf(w2, c0, am0); am1 = fmaf(w2, c1, am1);
        at0 = fmaf(u2, c0, at0); at1 = fmaf(u2, c1, at1);
        am0 = fmaf(w3, d0, am0); am1 = fmaf(w3, d1, am1);
        at0 = fmaf(u3, d0, at0); at1 = fmaf(u3, d1, at1);
    }
    for (; e < hi; ++e) {
        int4 r0 = rec[e];
        unsigned int v0 = *(const unsigned int*)(xh16 + (size_t)r0.x * 128 + l * 2);
        float w0 = __int_as_float(r0.y), u0 = __int_as_float(r0.z);
        float a0 = bf2f(v0 & 0xffff), a1 = bf2f(v0 >> 16);
        am0 = fmaf(w0, a0, am0); am1 = fmaf(w0, a1, am1);
        at0 = fmaf(u0, a0, at0); at1 = fmaf(u0, a1, at1);
    }
    float dd = deg[n];
    float dis_d = dd > 0.f ? rsqrtf(dd) : 0.f;
    int c = hi - lo;
    float ic = 1.f / (float)(c > 0 ? c : 1);
    unsigned int tpack = (unsigned int)f2bf(-dis_d * at0) |
                         ((unsigned int)f2bf(-dis_d * at1) << 16);
    unsigned int mpack = (unsigned int)f2bf(am0 * ic) |
                         ((unsigned int)f2bf(am1 * ic) << 16);
    tx16[(size_t)n * 64 + l] = tpack;
    mn16[(size_t)n * 64 + l] = mpack;
}

// ------------- fused epilogue (bf16 MFMA): o1, o2, s, o3 -------------
__global__ __launch_bounds__(256) void k_fused(const unsigned short* __restrict__ xh16,
                                               const unsigned short* __restrict__ tx16,
                                               const unsigned short* __restrict__ mn16,
                                               const unsigned short* __restrict__ Pall,
                                               const float* __restrict__ bc,
                                               const float* __restrict__ brel,
                                               const float* __restrict__ bl,
                                               float* __restrict__ out) {
    const unsigned short* Pc0  = Pall + 1 * 16384;
    const unsigned short* Pc1  = Pall + 2 * 16384;
    const unsigned short* Prel = Pall + 3 * 16384;
    const unsigned short* Proot= Pall + 4 * 16384;
    const unsigned short* Pl   = Pall + 5 * 16384;
    __shared__ __align__(16) unsigned short sS[4][16][136];
    int wave = threadIdx.x >> 6, l = threadIdx.x & 63;
    int n0 = blockIdx.x * 64 + wave * 16;
    int m = l & 15, q = l >> 4;
    int nodeA = n0 + m;
    bool av = nodeA < NN;
    size_t ra = (size_t)(av ? nodeA : 0) * 128 + q * 8;
    floatx4 acc1[8], acc2[8];
#pragma unroll
    for (int ct = 0; ct < 8; ++ct) { acc1[ct] = (floatx4)(0.f); acc2[ct] = (floatx4)(0.f); }
#pragma unroll
    for (int kc = 0; kc < 4; ++kc) {
        short8 a_xh = *(const short8*)(xh16 + ra + kc * 32);
        short8 a_tx = *(const short8*)(tx16 + ra + kc * 32);
        short8 a_mn = *(const short8*)(mn16 + ra + kc * 32);
#pragma unroll
        for (int ct = 0; ct < 8; ++ct) {
            int po = ((kc * 8 + ct) << 9) + l * 8;
            short8 b0 = *(const short8*)(Pc0 + po);
            short8 b1 = *(const short8*)(Pc1 + po);
            short8 b2 = *(const short8*)(Prel + po);
            short8 b3 = *(const short8*)(Proot + po);
            acc1[ct] = __builtin_amdgcn_mfma_f32_16x16x32_bf16(a_xh, b0, acc1[ct], 0, 0, 0);
            acc1[ct] = __builtin_amdgcn_mfma_f32_16x16x32_bf16(a_tx, b1, acc1[ct], 0, 0, 0);
            acc2[ct] = __builtin_amdgcn_mfma_f32_16x16x32_bf16(a_mn, b2, acc2[ct], 0, 0, 0);
            acc2[ct] = __builtin_amdgcn_mfma_f32_16x16x32_bf16(a_xh, b3, acc2[ct], 0, 0, 0);
        }
    }
#pragma unroll
    for (int ct = 0; ct < 8; ++ct) {
        int col = ct * 16 + m;
        float b1v = bc[col], b2v = brel[col];
#pragma unroll
        for (int r = 0; r < 4; ++r) {
            float u = leaky(acc1[ct][r] + b1v) + leaky(acc2[ct][r] + b2v);
            sS[wave][q * 4 + r][col] = f2bf(u);
        }
    }
    floatx4 acc3[8];
#pragma unroll
    for (int ct = 0; ct < 8; ++ct) acc3[ct] = (floatx4)(0.f);
#pragma unroll
    for (int kc = 0; kc < 4; ++kc) {
        short8 a_s = *(const short8*)&sS[wave][m][kc * 32 + q * 8];
#pragma unroll
        for (int ct = 0; ct < 8; ++ct) {
            short8 b = *(const short8*)(Pl + ((kc * 8 + ct) << 9) + l * 8);
            acc3[ct] = __builtin_amdgcn_mfma_f32_16x16x32_bf16(a_s, b, acc3[ct], 0, 0, 0);
        }
    }
#pragma unroll
    for (int ct = 0; ct < 8; ++ct) {
        int col = ct * 16 + m;
        float bv = bl[col];
#pragma unroll
        for (int r = 0; r < 4; ++r) {
            int node = n0 + q * 4 + r;
            if (node < NN) out[(size_t)node * 128 + col] = acc3[ct][r] + bv;
        }
    }
}

extern "C" void kernel_launch(void* const* d_in, const int* in_sizes, int n_in,
                              void* d_out, int out_size, void* d_ws, size_t ws_size,
                              hipStream_t stream) {
    const float* x    = (const float*)d_in[1];
    const int*   ei   = (const int*)d_in[2];
    const float* ew   = (const float*)d_in[3];
    const float* Wp   = (const float*)d_in[4];
    const float* bp   = (const float*)d_in[5];
    const float* Wc0  = (const float*)d_in[6];
    const float* Wc1  = (const float*)d_in[7];
    const float* bc   = (const float*)d_in[8];
    const float* Wrel = (const float*)d_in[9];
    const float* brel = (const float*)d_in[10];
    const float* Wroot= (const float*)d_in[11];
    const float* Wl   = (const float*)d_in[12];
    const float* bl   = (const float*)d_in[13];
    (void)in_sizes; (void)n_in; (void)out_size; (void)ws_size;
    float* out = (float*)d_out;

    unsigned short* xh16 = (unsigned short*)d_ws;        // NN*128 bf16
    unsigned short* tx16 = xh16 + (size_t)NN * 128;
    unsigned short* mn16 = tx16 + (size_t)NN * 128;
    unsigned short* Pall = mn16 + (size_t)NN * 128;      // 6*16384 bf16
    float* deg4   = (float*)(Pall + 6 * 16384);          // 4*NN (sharded deg)
    int*   cntI   = (int*)(deg4 + 4 * NN);               // NN (zeroed with deg4)
    int*   rank   = cntI + NN;                           // EE
    int4*  rec    = (int4*)(rank + EE);                  // EE int4 (16B-aligned)
    int*   rowstart = (int*)(rec + EE);                  // NN+1
    int*   blocksum = rowstart + NN + 2;                 // SBLK
    int*   blockoff = blocksum + SBLK + 1;               // SBLK
    float* deg    = (float*)(blockoff + SBLK + 1);       // NN (reduced)

    const int* srcI = ei;
    const int* dstI = ei + EE;

    // phase A: zero(deg4+cntI) ∥ pack weights — both must complete before k_front
    k_pre<<<ZRB + PKB, 256, 0, stream>>>(
        (float4*)deg4, Wp, Wc0, Wc1, Wrel, Wroot, Wl, Pall);
    // phase B: degrank (atomic-latency, 8 edges/thread) ∥ xh+his (MFMA/BW)
    k_front<<<DRB + XHB, 256, 0, stream>>>(
        srcI, dstI, ew, deg4, cntI, rank, x, bp, xh16, out, Pall);
    k_scan_part<<<SBLK, 256, 0, stream>>>(cntI, deg4, blocksum, deg);
    k_scan_mid<<<1, 64, 0, stream>>>(blocksum, blockoff, rowstart);
    k_scan_final<<<SBLK, 256, 0, stream>>>(cntI, blockoff, rowstart);
    k_bucket<<<(EE + 255) / 256, 256, 0, stream>>>(srcI, dstI, ew, deg, rowstart,
                                                   rank, rec);
    k_gather<<<(NN + 3) / 4, 256, 0, stream>>>(rowstart, rec, deg, xh16,
                                               (unsigned int*)tx16, (unsigned int*)mn16);
    k_fused<<<(NN + 63) / 64, 256, 0, stream>>>(xh16, tx16, mn16, Pall,
                                                bc, brel, bl, out + (size_t)NN * 128);
}

// Round 2
// 269.876 us; speedup vs baseline: 1.1912x; 1.1538x over previous
//
#include <hip/hip_runtime.h>

#define NN 50000
#define EE 800000
#define D  128
#define NCH 64         // edge chunks
#define CH  12500      // EE/NCH
#define NR  8          // dst/src ranges
#define RS  6250       // NN/NR
#define KCB 512        // NCH*NR count blocks
#define XHB 782        // xh blocks: ceil(NN/64)
#define CSB 196        // colscan/scan blocks: ceil(NN/256)
#define PKB 384        // pack blocks: 6*16384/256

typedef short short8 __attribute__((ext_vector_type(8)));
typedef float floatx4 __attribute__((ext_vector_type(4)));

__device__ __forceinline__ float leaky(float v) { return v > 0.f ? v : 0.01f * v; }

__device__ __forceinline__ unsigned short f2bf(float f) {
    unsigned int u = __float_as_uint(f);
    u = (u + 0x7fff + ((u >> 16) & 1)) >> 16;     // round-to-nearest-even
    return (unsigned short)u;
}
__device__ __forceinline__ float bf2f(unsigned int h) {
    return __uint_as_float(h << 16);
}

// ------------- phase A: pack weights to bf16 MFMA layout (no zeroing needed anymore) -------------
__global__ __launch_bounds__(256) void k_pre(
    const float* __restrict__ Wp,  const float* __restrict__ Wc0,
    const float* __restrict__ Wc1, const float* __restrict__ Wrel,
    const float* __restrict__ Wroot, const float* __restrict__ Wl,
    unsigned short* __restrict__ Pall) {
    int gid = blockIdx.x * 256 + threadIdx.x;
    int mm = gid >> 14;
    int r = gid & 16383;
    int j  = r & 7;
    int l  = (r >> 3) & 63;
    int ct = (r >> 9) & 7;
    int kc = r >> 12;
    int n = ct * 16 + (l & 15);
    int k = kc * 32 + (l >> 4) * 8 + j;
    const float* W = mm == 0 ? Wp : mm == 1 ? Wc0 : mm == 2 ? Wc1
                   : mm == 3 ? Wrel : mm == 4 ? Wroot : Wl;
    Pall[gid] = f2bf(W[n * 128 + k]);
}

// ------------- phase B: LDS-privatized count/degsum (NO global atomics) ∥ xh(+his copy) -------------
__global__ __launch_bounds__(256) void k_main(
    const int* __restrict__ src, const int* __restrict__ dst,
    const float* __restrict__ ew,
    int* __restrict__ counts,            // [NCH][NN] per-chunk dst counts
    float* __restrict__ degp,            // [NCH][NN] per-chunk src weighted-degree partials
    unsigned short* __restrict__ rank,   // [EE] within-(chunk,dst) rank
    const float* __restrict__ x, const float* __restrict__ bp,
    unsigned short* __restrict__ xh16, float* __restrict__ his,
    const unsigned short* __restrict__ Pall) {
    __shared__ int   scnt[RS];   // 25 KB
    __shared__ float sdeg[RS];   // 25 KB
    int b = blockIdx.x;
    if (b < KCB) {
        // chunk = b&63 so all 8 range-blocks of a chunk land on the same XCD (%8 RR):
        // chunk re-reads hit that XCD's L2 and scattered rank writes merge in one L2.
        int c = b & 63;
        int rge = b >> 6;
        int rlo = rge * RS;
        for (int i = threadIdx.x; i < RS; i += 256) { scnt[i] = 0; sdeg[i] = 0.f; }
        __syncthreads();
        int base = c * CH;
        for (int i0 = threadIdx.x * 4; i0 < CH; i0 += 1024) {
            int e = base + i0;
            int4   s4 = *(const int4*)(src + e);
            int4   d4 = *(const int4*)(dst + e);
            float4 w4 = *(const float4*)(ew + e);
            unsigned dr, sr;
            dr = (unsigned)(d4.x - rlo);
            if (dr < RS) rank[e]     = (unsigned short)atomicAdd(&scnt[dr], 1);
            sr = (unsigned)(s4.x - rlo);
            if (sr < RS) atomicAdd(&sdeg[sr], w4.x);
            dr = (unsigned)(d4.y - rlo);
            if (dr < RS) rank[e + 1] = (unsigned short)atomicAdd(&scnt[dr], 1);
            sr = (unsigned)(s4.y - rlo);
            if (sr < RS) atomicAdd(&sdeg[sr], w4.y);
            dr = (unsigned)(d4.z - rlo);
            if (dr < RS) rank[e + 2] = (unsigned short)atomicAdd(&scnt[dr], 1);
            sr = (unsigned)(s4.z - rlo);
            if (sr < RS) atomicAdd(&sdeg[sr], w4.z);
            dr = (unsigned)(d4.w - rlo);
            if (dr < RS) rank[e + 3] = (unsigned short)atomicAdd(&scnt[dr], 1);
            sr = (unsigned)(s4.w - rlo);
            if (sr < RS) atomicAdd(&sdeg[sr], w4.w);
        }
        __syncthreads();
        size_t ob = (size_t)c * NN + rlo;
        for (int i = threadIdx.x; i < RS; i += 256) {
            counts[ob + i] = scnt[i];
            degp[ob + i]   = sdeg[i];
        }
    } else {
        // ---- xh = x @ Wp^T + bp (bf16 MFMA) + his = x copy ----
        int bb = b - KCB;
        const unsigned short* Pp = Pall;   // slot 0
        int wave = threadIdx.x >> 6, l = threadIdx.x & 63;
        int n0 = bb * 64 + wave * 16;
        int m = l & 15, q = l >> 4;
        int nodeA = n0 + m;
        bool av = nodeA < NN;
        int na = av ? nodeA : 0;
        floatx4 acc[8];
#pragma unroll
        for (int ct = 0; ct < 8; ++ct) acc[ct] = (floatx4)(0.f);
#pragma unroll
        for (int kc = 0; kc < 4; ++kc) {
            const float* ap = x + (size_t)na * 128 + kc * 32 + q * 8;
            float4 f0 = av ? *(const float4*)ap       : make_float4(0, 0, 0, 0);
            float4 f1 = av ? *(const float4*)(ap + 4) : make_float4(0, 0, 0, 0);
            if (av) {
                float* hp = his + (size_t)nodeA * 128 + kc * 32 + q * 8;
                *(float4*)hp       = f0;
                *(float4*)(hp + 4) = f1;
            }
            short8 a;
            a[0] = f2bf(f0.x); a[1] = f2bf(f0.y); a[2] = f2bf(f0.z); a[3] = f2bf(f0.w);
            a[4] = f2bf(f1.x); a[5] = f2bf(f1.y); a[6] = f2bf(f1.z); a[7] = f2bf(f1.w);
#pragma unroll
            for (int ct = 0; ct < 8; ++ct) {
                short8 bfr = *(const short8*)(Pp + ((kc * 8 + ct) << 9) + l * 8);
                acc[ct] = __builtin_amdgcn_mfma_f32_16x16x32_bf16(a, bfr, acc[ct], 0, 0, 0);
            }
        }
#pragma unroll
        for (int ct = 0; ct < 8; ++ct) {
            int col = ct * 16 + m;
            float bias = bp[col];
#pragma unroll
            for (int r = 0; r < 4; ++r) {
                int node = n0 + q * 4 + r;
                if (node < NN) xh16[(size_t)node * 128 + col] = f2bf(acc[ct][r] + bias);
            }
        }
    }
}

// ------------- per-node scan over chunks: chunkoff (in-place), cntI total, deg sum, blocksum -------------
__global__ __launch_bounds__(256) void k_colscan(int* __restrict__ counts,
                                                 const float* __restrict__ degp,
                                                 int* __restrict__ cntI,
                                                 float* __restrict__ deg,
                                                 int* __restrict__ blocksum) {
    __shared__ int ws4[4];
    int t = threadIdx.x;
    int n = blockIdx.x * 256 + t;
    int acc = 0; float dacc = 0.f;
    if (n < NN) {
#pragma unroll 8
        for (int c = 0; c < NCH; ++c) {
            size_t idx = (size_t)c * NN + n;
            int v = counts[idx];
            counts[idx] = acc;      // exclusive prefix over chunks (chunkoff)
            acc += v;
            dacc += degp[idx];
        }
        cntI[n] = acc;
        deg[n] = dacc;
    }
    int s = (n < NN) ? acc : 0;
#pragma unroll
    for (int off = 32; off > 0; off >>= 1) s += __shfl_down(s, off, 64);
    if ((t & 63) == 0) ws4[t >> 6] = s;
    __syncthreads();
    if (t == 0) blocksum[blockIdx.x] = ws4[0] + ws4[1] + ws4[2] + ws4[3];
}

__global__ __launch_bounds__(256) void k_scan_mid(const int* __restrict__ blocksum,
                                                  int* __restrict__ blockoff,
                                                  int* __restrict__ rowstart) {
    __shared__ int wtot[4];
    int t = threadIdx.x, lane = t & 63, wave = t >> 6;
    int v = (t < CSB) ? blocksum[t] : 0;
    int incl = v;
#pragma unroll
    for (int off = 1; off < 64; off <<= 1) {
        int u = __shfl_up(incl, off, 64);
        if (lane >= off) incl += u;
    }
    if (lane == 63) wtot[wave] = incl;
    __syncthreads();
    int wpre = 0;
    for (int w = 0; w < wave; ++w) wpre += wtot[w];
    incl += wpre;
    if (t < CSB) blockoff[t] = incl - v;
    if (t == 255) rowstart[NN] = incl;
}

__global__ __launch_bounds__(256) void k_scan_final(const int* __restrict__ cntI,
                                                    const int* __restrict__ blockoff,
                                                    int* __restrict__ rowstart) {
    __shared__ int wtot[4];
    int t = threadIdx.x, lane = t & 63, wave = t >> 6;
    int n = blockIdx.x * 256 + t;
    int v = (n < NN) ? cntI[n] : 0;
    int incl = v;
#pragma unroll
    for (int off = 1; off < 64; off <<= 1) {
        int u = __shfl_up(incl, off, 64);
        if (lane >= off) incl += u;
    }
    if (lane == 63) wtot[wave] = incl;
    __syncthreads();
    int wpre = 0;
    for (int w = 0; w < wave; ++w) wpre += wtot[w];
    incl += wpre;
    if (n < NN) rowstart[n] = blockoff[blockIdx.x] + incl - v;
}

// ------------- bucket edges by dst, NO atomics: rec[pos] = {src, w, dis_s*w, 0} -------------
__global__ __launch_bounds__(256) void k_bucket(const int* __restrict__ src,
                                                const int* __restrict__ dst,
                                                const float* __restrict__ ew,
                                                const float* __restrict__ deg,
                                                const int* __restrict__ rowstart,
                                                const int* __restrict__ chunkoff,
                                                const unsigned short* __restrict__ rank,
                                                int4* __restrict__ rec) {
    int e = blockIdx.x * blockDim.x + threadIdx.x;
    if (e >= EE) return;
    int s = src[e], d = dst[e];
    float w = ew[e];
    float degs = deg[s];
    float dis_s = degs > 0.f ? rsqrtf(degs) : 0.f;
    int c = e / CH;
    int pos = rowstart[d] + chunkoff[(size_t)c * NN + d] + (int)rank[e];
    int4 r;
    r.x = s;
    r.y = __float_as_int(w);
    r.z = __float_as_int(dis_s * w);
    r.w = 0;
    rec[pos] = r;
}

// ------------- per-dst gather on bf16 xh: Tx1, mean → bf16 -------------
__global__ __launch_bounds__(256) void k_gather(const int* __restrict__ rowstart,
                                                const int4* __restrict__ rec,
                                                const float* __restrict__ deg,
                                                const unsigned short* __restrict__ xh16,
                                                unsigned int* __restrict__ tx16,
                                                unsigned int* __restrict__ mn16) {
    int wave = threadIdx.x >> 6, l = threadIdx.x & 63;
    int n = blockIdx.x * 4 + wave;
    if (n >= NN) return;
    int lo = rowstart[n], hi = rowstart[n + 1];
    float at0 = 0.f, at1 = 0.f, am0 = 0.f, am1 = 0.f;
    int e = lo;
    for (; e + 3 < hi; e += 4) {
        int4 r0 = rec[e], r1 = rec[e + 1], r2 = rec[e + 2], r3 = rec[e + 3];
        unsigned int v0 = *(const unsigned int*)(xh16 + (size_t)r0.x * 128 + l * 2);
        unsigned int v1 = *(const unsigned int*)(xh16 + (size_t)r1.x * 128 + l * 2);
        unsigned int v2 = *(const unsigned int*)(xh16 + (size_t)r2.x * 128 + l * 2);
        unsigned int v3 = *(const unsigned int*)(xh16 + (size_t)r3.x * 128 + l * 2);
        float w0 = __int_as_float(r0.y), u0 = __int_as_float(r0.z);
        float w1 = __int_as_float(r1.y), u1 = __int_as_float(r1.z);
        float w2 = __int_as_float(r2.y), u2 = __int_as_float(r2.z);
        float w3 = __int_as_float(r3.y), u3 = __int_as_float(r3.z);
        float a0 = bf2f(v0 & 0xffff), a1 = bf2f(v0 >> 16);
        float b0 = bf2f(v1 & 0xffff), b1 = bf2f(v1 >> 16);
        float c0 = bf2f(v2 & 0xffff), c1 = bf2f(v2 >> 16);
        float d0 = bf2f(v3 & 0xffff), d1 = bf2f(v3 >> 16);
        am0 = fmaf(w0, a0, am0); am1 = fmaf(w0, a1, am1);
        at0 = fmaf(u0, a0, at0); at1 = fmaf(u0, a1, at1);
        am0 = fmaf(w1, b0, am0); am1 = fmaf(w1, b1, am1);
        at0 = fmaf(u1, b0, at0); at1 = fmaf(u1, b1, at1);
        am0 = fmaf(w2, c0, am0); am1 = fmaf(w2, c1, am1);
        at0 = fmaf(u2, c0, at0); at1 = fmaf(u2, c1, at1);
        am0 = fmaf(w3, d0, am0); am1 = fmaf(w3, d1, am1);
        at0 = fmaf(u3, d0, at0); at1 = fmaf(u3, d1, at1);
    }
    for (; e < hi; ++e) {
        int4 r0 = rec[e];
        unsigned int v0 = *(const unsigned int*)(xh16 + (size_t)r0.x * 128 + l * 2);
        float w0 = __int_as_float(r0.y), u0 = __int_as_float(r0.z);
        float a0 = bf2f(v0 & 0xffff), a1 = bf2f(v0 >> 16);
        am0 = fmaf(w0, a0, am0); am1 = fmaf(w0, a1, am1);
        at0 = fmaf(u0, a0, at0); at1 = fmaf(u0, a1, at1);
    }
    float dd = deg[n];
    float dis_d = dd > 0.f ? rsqrtf(dd) : 0.f;
    int c = hi - lo;
    float ic = 1.f / (float)(c > 0 ? c : 1);
    unsigned int tpack = (unsigned int)f2bf(-dis_d * at0) |
                         ((unsigned int)f2bf(-dis_d * at1) << 16);
    unsigned int mpack = (unsigned int)f2bf(am0 * ic) |
                         ((unsigned int)f2bf(am1 * ic) << 16);
    tx16[(size_t)n * 64 + l] = tpack;
    mn16[(size_t)n * 64 + l] = mpack;
}

// ------------- fused epilogue (bf16 MFMA): o1, o2, s, o3 -------------
__global__ __launch_bounds__(256) void k_fused(const unsigned short* __restrict__ xh16,
                                               const unsigned short* __restrict__ tx16,
                                               const unsigned short* __restrict__ mn16,
                                               const unsigned short* __restrict__ Pall,
                                               const float* __restrict__ bc,
                                               const float* __restrict__ brel,
                                               const float* __restrict__ bl,
                                               float* __restrict__ out) {
    const unsigned short* Pc0  = Pall + 1 * 16384;
    const unsigned short* Pc1  = Pall + 2 * 16384;
    const unsigned short* Prel = Pall + 3 * 16384;
    const unsigned short* Proot= Pall + 4 * 16384;
    const unsigned short* Pl   = Pall + 5 * 16384;
    __shared__ __align__(16) unsigned short sS[4][16][136];
    int wave = threadIdx.x >> 6, l = threadIdx.x & 63;
    int n0 = blockIdx.x * 64 + wave * 16;
    int m = l & 15, q = l >> 4;
    int nodeA = n0 + m;
    bool av = nodeA < NN;
    size_t ra = (size_t)(av ? nodeA : 0) * 128 + q * 8;
    floatx4 acc1[8], acc2[8];
#pragma unroll
    for (int ct = 0; ct < 8; ++ct) { acc1[ct] = (floatx4)(0.f); acc2[ct] = (floatx4)(0.f); }
#pragma unroll
    for (int kc = 0; kc < 4; ++kc) {
        short8 a_xh = *(const short8*)(xh16 + ra + kc * 32);
        short8 a_tx = *(const short8*)(tx16 + ra + kc * 32);
        short8 a_mn = *(const short8*)(mn16 + ra + kc * 32);
#pragma unroll
        for (int ct = 0; ct < 8; ++ct) {
            int po = ((kc * 8 + ct) << 9) + l * 8;
            short8 b0 = *(const short8*)(Pc0 + po);
            short8 b1 = *(const short8*)(Pc1 + po);
            short8 b2 = *(const short8*)(Prel + po);
            short8 b3 = *(const short8*)(Proot + po);
            acc1[ct] = __builtin_amdgcn_mfma_f32_16x16x32_bf16(a_xh, b0, acc1[ct], 0, 0, 0);
            acc1[ct] = __builtin_amdgcn_mfma_f32_16x16x32_bf16(a_tx, b1, acc1[ct], 0, 0, 0);
            acc2[ct] = __builtin_amdgcn_mfma_f32_16x16x32_bf16(a_mn, b2, acc2[ct], 0, 0, 0);
            acc2[ct] = __builtin_amdgcn_mfma_f32_16x16x32_bf16(a_xh, b3, acc2[ct], 0, 0, 0);
        }
    }
#pragma unroll
    for (int ct = 0; ct < 8; ++ct) {
        int col = ct * 16 + m;
        float b1v = bc[col], b2v = brel[col];
#pragma unroll
        for (int r = 0; r < 4; ++r) {
            float u = leaky(acc1[ct][r] + b1v) + leaky(acc2[ct][r] + b2v);
            sS[wave][q * 4 + r][col] = f2bf(u);
        }
    }
    floatx4 acc3[8];
#pragma unroll
    for (int ct = 0; ct < 8; ++ct) acc3[ct] = (floatx4)(0.f);
#pragma unroll
    for (int kc = 0; kc < 4; ++kc) {
        short8 a_s = *(const short8*)&sS[wave][m][kc * 32 + q * 8];
#pragma unroll
        for (int ct = 0; ct < 8; ++ct) {
            short8 b = *(const short8*)(Pl + ((kc * 8 + ct) << 9) + l * 8);
            acc3[ct] = __builtin_amdgcn_mfma_f32_16x16x32_bf16(a_s, b, acc3[ct], 0, 0, 0);
        }
    }
#pragma unroll
    for (int ct = 0; ct < 8; ++ct) {
        int col = ct * 16 + m;
        float bv = bl[col];
#pragma unroll
        for (int r = 0; r < 4; ++r) {
            int node = n0 + q * 4 + r;
            if (node < NN) out[(size_t)node * 128 + col] = acc3[ct][r] + bv;
        }
    }
}

extern "C" void kernel_launch(void* const* d_in, const int* in_sizes, int n_in,
                              void* d_out, int out_size, void* d_ws, size_t ws_size,
                              hipStream_t stream) {
    const float* x    = (const float*)d_in[1];
    const int*   ei   = (const int*)d_in[2];
    const float* ew   = (const float*)d_in[3];
    const float* Wp   = (const float*)d_in[4];
    const float* bp   = (const float*)d_in[5];
    const float* Wc0  = (const float*)d_in[6];
    const float* Wc1  = (const float*)d_in[7];
    const float* bc   = (const float*)d_in[8];
    const float* Wrel = (const float*)d_in[9];
    const float* brel = (const float*)d_in[10];
    const float* Wroot= (const float*)d_in[11];
    const float* Wl   = (const float*)d_in[12];
    const float* bl   = (const float*)d_in[13];
    (void)in_sizes; (void)n_in; (void)out_size; (void)ws_size;
    float* out = (float*)d_out;

    unsigned short* xh16 = (unsigned short*)d_ws;        // NN*128 bf16
    unsigned short* tx16 = xh16 + (size_t)NN * 128;
    unsigned short* mn16 = tx16 + (size_t)NN * 128;
    unsigned short* Pall = mn16 + (size_t)NN * 128;      // 6*16384 bf16
    int*   counts = (int*)(Pall + 6 * 16384);            // [NCH][NN] -> chunkoff (in-place)
    int4*  rec    = (int4*)(counts + (size_t)NCH * NN);  // EE int4; degp aliases (dead before rec written)
    float* degp   = (float*)rec;                         // [NCH][NN] floats == EE*16 bytes
    unsigned short* rank = (unsigned short*)(rec + EE);  // EE ushort (lrank < CH=12500)
    int*   rowstart = (int*)(rank + EE);                 // NN+1
    int*   blocksum = rowstart + NN + 2;                 // CSB
    int*   blockoff = blocksum + CSB;                    // CSB
    int*   cntI   = blockoff + CSB;                      // NN
    float* deg    = (float*)(cntI + NN);                 // NN

    const int* srcI = ei;
    const int* dstI = ei + EE;

    // phase A: pack weights (must complete before k_main's xh path reads Pall)
    k_pre<<<PKB, 256, 0, stream>>>(Wp, Wc0, Wc1, Wrel, Wroot, Wl, Pall);
    // phase B: LDS counting sort prep (no global atomics) ∥ xh+his (MFMA/BW)
    k_main<<<KCB + XHB, 256, 0, stream>>>(
        srcI, dstI, ew, counts, degp, rank, x, bp, xh16, out, Pall);
    k_colscan<<<CSB, 256, 0, stream>>>(counts, degp, cntI, deg, blocksum);
    k_scan_mid<<<1, 256, 0, stream>>>(blocksum, blockoff, rowstart);
    k_scan_final<<<CSB, 256, 0, stream>>>(cntI, blockoff, rowstart);
    k_bucket<<<(EE + 255) / 256, 256, 0, stream>>>(srcI, dstI, ew, deg, rowstart,
                                                   counts, rank, rec);
    k_gather<<<(NN + 3) / 4, 256, 0, stream>>>(rowstart, rec, deg, xh16,
                                               (unsigned int*)tx16, (unsigned int*)mn16);
    k_fused<<<(NN + 63) / 64, 256, 0, stream>>>(xh16, tx16, mn16, Pall,
                                                bc, brel, bl, out + (size_t)NN * 128);
}

// Round 3
// 266.028 us; speedup vs baseline: 1.2085x; 1.0145x over previous
//
#include <hip/hip_runtime.h>

#define NN 50000
#define EE 800000
#define D  128
#define NCH 64         // edge chunks
#define CH  12500      // EE/NCH
#define NR  8          // dst/src ranges
#define RS  6250       // NN/NR
#define KCB 512        // NCH*NR count blocks
#define XHB 782        // xh blocks: ceil(NN/64)
#define CSB 196        // colscan/scan blocks: ceil(NN/256)
#define PKB 384        // pack blocks: 6*16384/256
#define FB  391        // fused blocks: ceil(NN/128), 4 waves x 32 nodes

typedef short short8 __attribute__((ext_vector_type(8)));
typedef float floatx4 __attribute__((ext_vector_type(4)));
typedef float floatx16 __attribute__((ext_vector_type(16)));

__device__ __forceinline__ float leaky(float v) { return v > 0.f ? v : 0.01f * v; }

__device__ __forceinline__ unsigned short f2bf(float f) {
    unsigned int u = __float_as_uint(f);
    u = (u + 0x7fff + ((u >> 16) & 1)) >> 16;     // round-to-nearest-even
    return (unsigned short)u;
}
__device__ __forceinline__ float bf2f(unsigned int h) {
    return __uint_as_float(h << 16);
}

// ------------- phase A: pack weights to bf16 MFMA layouts -------------
// slot 0 (Wp): 16x16x32 layout (k_main's xh GEMM, unchanged)
// slots 1-5:   32x32x16 layout (k_fused)
__global__ __launch_bounds__(256) void k_pre(
    const float* __restrict__ Wp,  const float* __restrict__ Wc0,
    const float* __restrict__ Wc1, const float* __restrict__ Wrel,
    const float* __restrict__ Wroot, const float* __restrict__ Wl,
    unsigned short* __restrict__ Pall) {
    int gid = blockIdx.x * 256 + threadIdx.x;
    int mm = gid >> 14;
    int r = gid & 16383;
    int j  = r & 7;
    int l  = (r >> 3) & 63;
    int n, k;
    if (mm == 0) {                  // 16x16x32: frag (kc,ct), n=ct*16+(l&15), k=kc*32+(l>>4)*8+j
        int ct = (r >> 9) & 7;
        int kc = r >> 12;
        n = ct * 16 + (l & 15);
        k = kc * 32 + (l >> 4) * 8 + j;
    } else {                        // 32x32x16: frag (kc,ct), n=ct*32+(l&31), k=kc*16+(l>>5)*8+j
        int ct = (r >> 9) & 3;
        int kc = (r >> 11) & 7;
        n = ct * 32 + (l & 31);
        k = kc * 16 + (l >> 5) * 8 + j;
    }
    const float* W = mm == 0 ? Wp : mm == 1 ? Wc0 : mm == 2 ? Wc1
                   : mm == 3 ? Wrel : mm == 4 ? Wroot : Wl;
    Pall[gid] = f2bf(W[n * 128 + k]);
}

// ------------- phase B: LDS-privatized count/degsum (NO global atomics) ∥ xh(+his copy) -------------
__global__ __launch_bounds__(256) void k_main(
    const int* __restrict__ src, const int* __restrict__ dst,
    const float* __restrict__ ew,
    int* __restrict__ counts,            // [NCH][NN] per-chunk dst counts
    float* __restrict__ degp,            // [NCH][NN] per-chunk src weighted-degree partials
    unsigned short* __restrict__ rank,   // [EE] within-(chunk,dst) rank
    const float* __restrict__ x, const float* __restrict__ bp,
    unsigned short* __restrict__ xh16, float* __restrict__ his,
    const unsigned short* __restrict__ Pall) {
    __shared__ int   scnt[RS];   // 25 KB
    __shared__ float sdeg[RS];   // 25 KB
    int b = blockIdx.x;
    if (b < KCB) {
        // chunk = b&63 so all 8 range-blocks of a chunk land on the same XCD (%8 RR):
        // chunk re-reads hit that XCD's L2 and scattered rank writes merge in one L2.
        int c = b & 63;
        int rge = b >> 6;
        int rlo = rge * RS;
        for (int i = threadIdx.x; i < RS; i += 256) { scnt[i] = 0; sdeg[i] = 0.f; }
        __syncthreads();
        int base = c * CH;
        for (int i0 = threadIdx.x * 4; i0 < CH; i0 += 1024) {
            int e = base + i0;
            int4   s4 = *(const int4*)(src + e);
            int4   d4 = *(const int4*)(dst + e);
            float4 w4 = *(const float4*)(ew + e);
            unsigned dr, sr;
            dr = (unsigned)(d4.x - rlo);
            if (dr < RS) rank[e]     = (unsigned short)atomicAdd(&scnt[dr], 1);
            sr = (unsigned)(s4.x - rlo);
            if (sr < RS) atomicAdd(&sdeg[sr], w4.x);
            dr = (unsigned)(d4.y - rlo);
            if (dr < RS) rank[e + 1] = (unsigned short)atomicAdd(&scnt[dr], 1);
            sr = (unsigned)(s4.y - rlo);
            if (sr < RS) atomicAdd(&sdeg[sr], w4.y);
            dr = (unsigned)(d4.z - rlo);
            if (dr < RS) rank[e + 2] = (unsigned short)atomicAdd(&scnt[dr], 1);
            sr = (unsigned)(s4.z - rlo);
            if (sr < RS) atomicAdd(&sdeg[sr], w4.z);
            dr = (unsigned)(d4.w - rlo);
            if (dr < RS) rank[e + 3] = (unsigned short)atomicAdd(&scnt[dr], 1);
            sr = (unsigned)(s4.w - rlo);
            if (sr < RS) atomicAdd(&sdeg[sr], w4.w);
        }
        __syncthreads();
        size_t ob = (size_t)c * NN + rlo;
        for (int i = threadIdx.x; i < RS; i += 256) {
            counts[ob + i] = scnt[i];
            degp[ob + i]   = sdeg[i];
        }
    } else {
        // ---- xh = x @ Wp^T + bp (bf16 MFMA, 16x16x32) + his = x copy ----
        int bb = b - KCB;
        const unsigned short* Pp = Pall;   // slot 0
        int wave = threadIdx.x >> 6, l = threadIdx.x & 63;
        int n0 = bb * 64 + wave * 16;
        int m = l & 15, q = l >> 4;
        int nodeA = n0 + m;
        bool av = nodeA < NN;
        int na = av ? nodeA : 0;
        floatx4 acc[8];
#pragma unroll
        for (int ct = 0; ct < 8; ++ct) acc[ct] = (floatx4)(0.f);
#pragma unroll
        for (int kc = 0; kc < 4; ++kc) {
            const float* ap = x + (size_t)na * 128 + kc * 32 + q * 8;
            float4 f0 = av ? *(const float4*)ap       : make_float4(0, 0, 0, 0);
            float4 f1 = av ? *(const float4*)(ap + 4) : make_float4(0, 0, 0, 0);
            if (av) {
                float* hp = his + (size_t)nodeA * 128 + kc * 32 + q * 8;
                *(float4*)hp       = f0;
                *(float4*)(hp + 4) = f1;
            }
            short8 a;
            a[0] = f2bf(f0.x); a[1] = f2bf(f0.y); a[2] = f2bf(f0.z); a[3] = f2bf(f0.w);
            a[4] = f2bf(f1.x); a[5] = f2bf(f1.y); a[6] = f2bf(f1.z); a[7] = f2bf(f1.w);
#pragma unroll
            for (int ct = 0; ct < 8; ++ct) {
                short8 bfr = *(const short8*)(Pp + ((kc * 8 + ct) << 9) + l * 8);
                acc[ct] = __builtin_amdgcn_mfma_f32_16x16x32_bf16(a, bfr, acc[ct], 0, 0, 0);
            }
        }
#pragma unroll
        for (int ct = 0; ct < 8; ++ct) {
            int col = ct * 16 + m;
            float bias = bp[col];
#pragma unroll
            for (int r = 0; r < 4; ++r) {
                int node = n0 + q * 4 + r;
                if (node < NN) xh16[(size_t)node * 128 + col] = f2bf(acc[ct][r] + bias);
            }
        }
    }
}

// ------------- per-node scan over chunks: chunkoff (in-place), cntI total, deg sum, blocksum -------------
__global__ __launch_bounds__(256) void k_colscan(int* __restrict__ counts,
                                                 const float* __restrict__ degp,
                                                 int* __restrict__ cntI,
                                                 float* __restrict__ deg,
                                                 int* __restrict__ blocksum) {
    __shared__ int ws4[4];
    int t = threadIdx.x;
    int n = blockIdx.x * 256 + t;
    int acc = 0; float dacc = 0.f;
    if (n < NN) {
#pragma unroll 8
        for (int c = 0; c < NCH; ++c) {
            size_t idx = (size_t)c * NN + n;
            int v = counts[idx];
            counts[idx] = acc;      // exclusive prefix over chunks (chunkoff)
            acc += v;
            dacc += degp[idx];
        }
        cntI[n] = acc;
        deg[n] = dacc;
    }
    int s = (n < NN) ? acc : 0;
#pragma unroll
    for (int off = 32; off > 0; off >>= 1) s += __shfl_down(s, off, 64);
    if ((t & 63) == 0) ws4[t >> 6] = s;
    __syncthreads();
    if (t == 0) blocksum[blockIdx.x] = ws4[0] + ws4[1] + ws4[2] + ws4[3];
}

__global__ __launch_bounds__(256) void k_scan_mid(const int* __restrict__ blocksum,
                                                  int* __restrict__ blockoff,
                                                  int* __restrict__ rowstart) {
    __shared__ int wtot[4];
    int t = threadIdx.x, lane = t & 63, wave = t >> 6;
    int v = (t < CSB) ? blocksum[t] : 0;
    int incl = v;
#pragma unroll
    for (int off = 1; off < 64; off <<= 1) {
        int u = __shfl_up(incl, off, 64);
        if (lane >= off) incl += u;
    }
    if (lane == 63) wtot[wave] = incl;
    __syncthreads();
    int wpre = 0;
    for (int w = 0; w < wave; ++w) wpre += wtot[w];
    incl += wpre;
    if (t < CSB) blockoff[t] = incl - v;
    if (t == 255) rowstart[NN] = incl;
}

__global__ __launch_bounds__(256) void k_scan_final(const int* __restrict__ cntI,
                                                    const int* __restrict__ blockoff,
                                                    int* __restrict__ rowstart) {
    __shared__ int wtot[4];
    int t = threadIdx.x, lane = t & 63, wave = t >> 6;
    int n = blockIdx.x * 256 + t;
    int v = (n < NN) ? cntI[n] : 0;
    int incl = v;
#pragma unroll
    for (int off = 1; off < 64; off <<= 1) {
        int u = __shfl_up(incl, off, 64);
        if (lane >= off) incl += u;
    }
    if (lane == 63) wtot[wave] = incl;
    __syncthreads();
    int wpre = 0;
    for (int w = 0; w < wave; ++w) wpre += wtot[w];
    incl += wpre;
    if (n < NN) rowstart[n] = blockoff[blockIdx.x] + incl - v;
}

// ------------- bucket edges by dst, NO atomics: rec[pos] = {src, w, dis_s*w, 0} -------------
__global__ __launch_bounds__(256) void k_bucket(const int* __restrict__ src,
                                                const int* __restrict__ dst,
                                                const float* __restrict__ ew,
                                                const float* __restrict__ deg,
                                                const int* __restrict__ rowstart,
                                                const int* __restrict__ chunkoff,
                                                const unsigned short* __restrict__ rank,
                                                int4* __restrict__ rec) {
    int e = blockIdx.x * blockDim.x + threadIdx.x;
    if (e >= EE) return;
    int s = src[e], d = dst[e];
    float w = ew[e];
    float degs = deg[s];
    float dis_s = degs > 0.f ? rsqrtf(degs) : 0.f;
    int c = e / CH;
    int pos = rowstart[d] + chunkoff[(size_t)c * NN + d] + (int)rank[e];
    int4 r;
    r.x = s;
    r.y = __float_as_int(w);
    r.z = __float_as_int(dis_s * w);
    r.w = 0;
    rec[pos] = r;
}

// ------------- per-dst gather on bf16 xh: Tx1, mean → bf16 -------------
__global__ __launch_bounds__(256) void k_gather(const int* __restrict__ rowstart,
                                                const int4* __restrict__ rec,
                                                const float* __restrict__ deg,
                                                const unsigned short* __restrict__ xh16,
                                                unsigned int* __restrict__ tx16,
                                                unsigned int* __restrict__ mn16) {
    int wave = threadIdx.x >> 6, l = threadIdx.x & 63;
    int n = blockIdx.x * 4 + wave;
    if (n >= NN) return;
    int lo = rowstart[n], hi = rowstart[n + 1];
    float at0 = 0.f, at1 = 0.f, am0 = 0.f, am1 = 0.f;
    int e = lo;
    for (; e + 3 < hi; e += 4) {
        int4 r0 = rec[e], r1 = rec[e + 1], r2 = rec[e + 2], r3 = rec[e + 3];
        unsigned int v0 = *(const unsigned int*)(xh16 + (size_t)r0.x * 128 + l * 2);
        unsigned int v1 = *(const unsigned int*)(xh16 + (size_t)r1.x * 128 + l * 2);
        unsigned int v2 = *(const unsigned int*)(xh16 + (size_t)r2.x * 128 + l * 2);
        unsigned int v3 = *(const unsigned int*)(xh16 + (size_t)r3.x * 128 + l * 2);
        float w0 = __int_as_float(r0.y), u0 = __int_as_float(r0.z);
        float w1 = __int_as_float(r1.y), u1 = __int_as_float(r1.z);
        float w2 = __int_as_float(r2.y), u2 = __int_as_float(r2.z);
        float w3 = __int_as_float(r3.y), u3 = __int_as_float(r3.z);
        float a0 = bf2f(v0 & 0xffff), a1 = bf2f(v0 >> 16);
        float b0 = bf2f(v1 & 0xffff), b1 = bf2f(v1 >> 16);
        float c0 = bf2f(v2 & 0xffff), c1 = bf2f(v2 >> 16);
        float d0 = bf2f(v3 & 0xffff), d1 = bf2f(v3 >> 16);
        am0 = fmaf(w0, a0, am0); am1 = fmaf(w0, a1, am1);
        at0 = fmaf(u0, a0, at0); at1 = fmaf(u0, a1, at1);
        am0 = fmaf(w1, b0, am0); am1 = fmaf(w1, b1, am1);
        at0 = fmaf(u1, b0, at0); at1 = fmaf(u1, b1, at1);
        am0 = fmaf(w2, c0, am0); am1 = fmaf(w2, c1, am1);
        at0 = fmaf(u2, c0, at0); at1 = fmaf(u2, c1, at1);
        am0 = fmaf(w3, d0, am0); am1 = fmaf(w3, d1, am1);
        at0 = fmaf(u3, d0, at0); at1 = fmaf(u3, d1, at1);
    }
    for (; e < hi; ++e) {
        int4 r0 = rec[e];
        unsigned int v0 = *(const unsigned int*)(xh16 + (size_t)r0.x * 128 + l * 2);
        float w0 = __int_as_float(r0.y), u0 = __int_as_float(r0.z);
        float a0 = bf2f(v0 & 0xffff), a1 = bf2f(v0 >> 16);
        am0 = fmaf(w0, a0, am0); am1 = fmaf(w0, a1, am1);
        at0 = fmaf(u0, a0, at0); at1 = fmaf(u0, a1, at1);
    }
    float dd = deg[n];
    float dis_d = dd > 0.f ? rsqrtf(dd) : 0.f;
    int c = hi - lo;
    float ic = 1.f / (float)(c > 0 ? c : 1);
    unsigned int tpack = (unsigned int)f2bf(-dis_d * at0) |
                         ((unsigned int)f2bf(-dis_d * at1) << 16);
    unsigned int mpack = (unsigned int)f2bf(am0 * ic) |
                         ((unsigned int)f2bf(am1 * ic) << 16);
    tx16[(size_t)n * 64 + l] = tpack;
    mn16[(size_t)n * 64 + l] = mpack;
}

// ------------- fused epilogue (bf16 MFMA 32x32x16, ct-outer): o1, o2, s, o3 -------------
// Each wave: 32 nodes. A (xh/tx/mn x 8 kc) register-resident; acc lives per-ct only
// (32 VGPRs) so the allocator can pipeline the B-fragment loads. Stage-1 -> stage-2
// transpose via per-wave LDS tile with 16B-group XOR swizzle (linear = 32-way conflict).
__global__ __launch_bounds__(256, 2) void k_fused(const unsigned short* __restrict__ xh16,
                                               const unsigned short* __restrict__ tx16,
                                               const unsigned short* __restrict__ mn16,
                                               const unsigned short* __restrict__ Pall,
                                               const float* __restrict__ bc,
                                               const float* __restrict__ brel,
                                               const float* __restrict__ bl,
                                               float* __restrict__ out) {
    const unsigned short* Pc0  = Pall + 1 * 16384;
    const unsigned short* Pc1  = Pall + 2 * 16384;
    const unsigned short* Prel = Pall + 3 * 16384;
    const unsigned short* Proot= Pall + 4 * 16384;
    const unsigned short* Pl   = Pall + 5 * 16384;
    __shared__ __align__(16) unsigned short sS[4][32][128];
    int w = threadIdx.x >> 6, l = threadIdx.x & 63;
    int n0 = blockIdx.x * 128 + w * 32;
    int row = l & 31, half = l >> 5;
    int node = n0 + row;
    bool av = node < NN;
    size_t ra = (size_t)(av ? node : 0) * 128 + half * 8;   // + kc*16
    short8 Axh[8], Atx[8], Amn[8];
#pragma unroll
    for (int kc = 0; kc < 8; ++kc) {
        Axh[kc] = *(const short8*)(xh16 + ra + kc * 16);
        Atx[kc] = *(const short8*)(tx16 + ra + kc * 16);
        Amn[kc] = *(const short8*)(mn16 + ra + kc * 16);
    }
#pragma unroll
    for (int ct = 0; ct < 4; ++ct) {
        floatx16 acc1 = (floatx16)(0.f), acc2 = (floatx16)(0.f);
#pragma unroll
        for (int kc = 0; kc < 8; ++kc) {
            int po = ((kc * 4 + ct) << 9) + l * 8;
            short8 b0 = *(const short8*)(Pc0 + po);
            short8 b1 = *(const short8*)(Pc1 + po);
            short8 b2 = *(const short8*)(Prel + po);
            short8 b3 = *(const short8*)(Proot + po);
            acc1 = __builtin_amdgcn_mfma_f32_32x32x16_bf16(Axh[kc], b0, acc1, 0, 0, 0);
            acc1 = __builtin_amdgcn_mfma_f32_32x32x16_bf16(Atx[kc], b1, acc1, 0, 0, 0);
            acc2 = __builtin_amdgcn_mfma_f32_32x32x16_bf16(Amn[kc], b2, acc2, 0, 0, 0);
            acc2 = __builtin_amdgcn_mfma_f32_32x32x16_bf16(Axh[kc], b3, acc2, 0, 0, 0);
        }
        int col = ct * 32 + row;
        float b1v = bc[col], b2v = brel[col];
#pragma unroll
        for (int r = 0; r < 16; ++r) {
            int rr = (r & 3) + 8 * (r >> 2) + 4 * half;     // C/D row map (m74/m101)
            float u = leaky(acc1[r] + b1v) + leaky(acc2[r] + b2v);
            int sw = ((((col >> 3) ^ rr) & 15) << 3) | (col & 7);
            sS[w][rr][sw] = f2bf(u);
        }
    }
    // stage 2: o3 = s @ Wl^T + bl  (A = sS rows via swizzled b128 reads)
    short8 As[8];
#pragma unroll
    for (int kc = 0; kc < 8; ++kc) {
        int g = (kc * 2 + half) ^ (row & 15);
        As[kc] = *(const short8*)&sS[w][row][g << 3];
    }
#pragma unroll
    for (int ct = 0; ct < 4; ++ct) {
        floatx16 acc3 = (floatx16)(0.f);
#pragma unroll
        for (int kc = 0; kc < 8; ++kc) {
            short8 b = *(const short8*)(Pl + ((kc * 4 + ct) << 9) + l * 8);
            acc3 = __builtin_amdgcn_mfma_f32_32x32x16_bf16(As[kc], b, acc3, 0, 0, 0);
        }
        int col = ct * 32 + row;
        float bv = bl[col];
#pragma unroll
        for (int r = 0; r < 16; ++r) {
            int rr = (r & 3) + 8 * (r >> 2) + 4 * half;
            int nd = n0 + rr;
            if (nd < NN) out[(size_t)nd * 128 + col] = acc3[r] + bv;
        }
    }
}

extern "C" void kernel_launch(void* const* d_in, const int* in_sizes, int n_in,
                              void* d_out, int out_size, void* d_ws, size_t ws_size,
                              hipStream_t stream) {
    const float* x    = (const float*)d_in[1];
    const int*   ei   = (const int*)d_in[2];
    const float* ew   = (const float*)d_in[3];
    const float* Wp   = (const float*)d_in[4];
    const float* bp   = (const float*)d_in[5];
    const float* Wc0  = (const float*)d_in[6];
    const float* Wc1  = (const float*)d_in[7];
    const float* bc   = (const float*)d_in[8];
    const float* Wrel = (const float*)d_in[9];
    const float* brel = (const float*)d_in[10];
    const float* Wroot= (const float*)d_in[11];
    const float* Wl   = (const float*)d_in[12];
    const float* bl   = (const float*)d_in[13];
    (void)in_sizes; (void)n_in; (void)out_size; (void)ws_size;
    float* out = (float*)d_out;

    unsigned short* xh16 = (unsigned short*)d_ws;        // NN*128 bf16
    unsigned short* tx16 = xh16 + (size_t)NN * 128;
    unsigned short* mn16 = tx16 + (size_t)NN * 128;
    unsigned short* Pall = mn16 + (size_t)NN * 128;      // 6*16384 bf16
    int*   counts = (int*)(Pall + 6 * 16384);            // [NCH][NN] -> chunkoff (in-place)
    int4*  rec    = (int4*)(counts + (size_t)NCH * NN);  // EE int4; degp aliases (dead before rec written)
    float* degp   = (float*)rec;                         // [NCH][NN] floats == EE*16 bytes
    unsigned short* rank = (unsigned short*)(rec + EE);  // EE ushort (lrank < CH=12500)
    int*   rowstart = (int*)(rank + EE);                 // NN+1
    int*   blocksum = rowstart + NN + 2;                 // CSB
    int*   blockoff = blocksum + CSB;                    // CSB
    int*   cntI   = blockoff + CSB;                      // NN
    float* deg    = (float*)(cntI + NN);                 // NN

    const int* srcI = ei;
    const int* dstI = ei + EE;

    // phase A: pack weights (must complete before k_main's xh path reads Pall)
    k_pre<<<PKB, 256, 0, stream>>>(Wp, Wc0, Wc1, Wrel, Wroot, Wl, Pall);
    // phase B: LDS counting sort prep (no global atomics) ∥ xh+his (MFMA/BW)
    k_main<<<KCB + XHB, 256, 0, stream>>>(
        srcI, dstI, ew, counts, degp, rank, x, bp, xh16, out, Pall);
    k_colscan<<<CSB, 256, 0, stream>>>(counts, degp, cntI, deg, blocksum);
    k_scan_mid<<<1, 256, 0, stream>>>(blocksum, blockoff, rowstart);
    k_scan_final<<<CSB, 256, 0, stream>>>(cntI, blockoff, rowstart);
    k_bucket<<<(EE + 255) / 256, 256, 0, stream>>>(srcI, dstI, ew, deg, rowstart,
                                                   counts, rank, rec);
    k_gather<<<(NN + 3) / 4, 256, 0, stream>>>(rowstart, rec, deg, xh16,
                                               (unsigned int*)tx16, (unsigned int*)mn16);
    k_fused<<<FB, 256, 0, stream>>>(xh16, tx16, mn16, Pall,
                                    bc, brel, bl, out + (size_t)NN * 128);
}

// Round 4
// 257.483 us; speedup vs baseline: 1.2486x; 1.0332x over previous
//
#include <hip/hip_runtime.h>

#define NN 50000
#define EE 800000
#define D  128
#define NCH 64         // edge chunks
#define CH  12500      // EE/NCH
#define NR  8          // dst/src ranges
#define RS  6250       // NN/NR
#define KCB 512        // NCH*NR count blocks
#define XHB 782        // xh blocks: ceil(NN/64)
#define CSB 196        // colscan/scan blocks: ceil(NN/256)
#define PKB 384        // pack blocks: 6*16384/256
#define FB  1563       // fused blocks: ceil(NN/32); 4 waves split the 4 col-quadrants

typedef short short8 __attribute__((ext_vector_type(8)));
typedef float floatx4 __attribute__((ext_vector_type(4)));
typedef float floatx16 __attribute__((ext_vector_type(16)));

__device__ __forceinline__ float leaky(float v) { return v > 0.f ? v : 0.01f * v; }

__device__ __forceinline__ unsigned short f2bf(float f) {
    unsigned int u = __float_as_uint(f);
    u = (u + 0x7fff + ((u >> 16) & 1)) >> 16;     // round-to-nearest-even
    return (unsigned short)u;
}
__device__ __forceinline__ float bf2f(unsigned int h) {
    return __uint_as_float(h << 16);
}

// ------------- phase A: pack weights to bf16 MFMA layouts -------------
// slot 0 (Wp): 16x16x32 layout (k_main's xh GEMM)
// slots 1-5:   32x32x16 layout (k_fused)
__global__ __launch_bounds__(256) void k_pre(
    const float* __restrict__ Wp,  const float* __restrict__ Wc0,
    const float* __restrict__ Wc1, const float* __restrict__ Wrel,
    const float* __restrict__ Wroot, const float* __restrict__ Wl,
    unsigned short* __restrict__ Pall) {
    int gid = blockIdx.x * 256 + threadIdx.x;
    int mm = gid >> 14;
    int r = gid & 16383;
    int j  = r & 7;
    int l  = (r >> 3) & 63;
    int n, k;
    if (mm == 0) {                  // 16x16x32: frag (kc,ct), n=ct*16+(l&15), k=kc*32+(l>>4)*8+j
        int ct = (r >> 9) & 7;
        int kc = r >> 12;
        n = ct * 16 + (l & 15);
        k = kc * 32 + (l >> 4) * 8 + j;
    } else {                        // 32x32x16: frag (kc,ct), n=ct*32+(l&31), k=kc*16+(l>>5)*8+j
        int ct = (r >> 9) & 3;
        int kc = (r >> 11) & 7;
        n = ct * 32 + (l & 31);
        k = kc * 16 + (l >> 5) * 8 + j;
    }
    const float* W = mm == 0 ? Wp : mm == 1 ? Wc0 : mm == 2 ? Wc1
                   : mm == 3 ? Wrel : mm == 4 ? Wroot : Wl;
    Pall[gid] = f2bf(W[n * 128 + k]);
}

// ------------- phase B: LDS-privatized count/degsum (NO global atomics) ∥ xh(+his copy) -------------
__global__ __launch_bounds__(256) void k_main(
    const int* __restrict__ src, const int* __restrict__ dst,
    const float* __restrict__ ew,
    int* __restrict__ counts,            // [NCH][NN] per-chunk dst counts
    float* __restrict__ degp,            // [NCH][NN] per-chunk src weighted-degree partials
    unsigned short* __restrict__ rank,   // [EE] within-(chunk,dst) rank
    const float* __restrict__ x, const float* __restrict__ bp,
    unsigned short* __restrict__ xh16, float* __restrict__ his,
    const unsigned short* __restrict__ Pall) {
    __shared__ int   scnt[RS];   // 25 KB
    __shared__ float sdeg[RS];   // 25 KB
    int b = blockIdx.x;
    if (b < KCB) {
        // chunk = b&63 so all 8 range-blocks of a chunk land on the same XCD (%8 RR):
        // chunk re-reads hit that XCD's L2 and scattered rank writes merge in one L2.
        int c = b & 63;
        int rge = b >> 6;
        int rlo = rge * RS;
        for (int i = threadIdx.x; i < RS; i += 256) { scnt[i] = 0; sdeg[i] = 0.f; }
        __syncthreads();
        int base = c * CH;
        for (int i0 = threadIdx.x * 4; i0 < CH; i0 += 1024) {
            int e = base + i0;
            int4   s4 = *(const int4*)(src + e);
            int4   d4 = *(const int4*)(dst + e);
            float4 w4 = *(const float4*)(ew + e);
            unsigned dr, sr;
            dr = (unsigned)(d4.x - rlo);
            if (dr < RS) rank[e]     = (unsigned short)atomicAdd(&scnt[dr], 1);
            sr = (unsigned)(s4.x - rlo);
            if (sr < RS) atomicAdd(&sdeg[sr], w4.x);
            dr = (unsigned)(d4.y - rlo);
            if (dr < RS) rank[e + 1] = (unsigned short)atomicAdd(&scnt[dr], 1);
            sr = (unsigned)(s4.y - rlo);
            if (sr < RS) atomicAdd(&sdeg[sr], w4.y);
            dr = (unsigned)(d4.z - rlo);
            if (dr < RS) rank[e + 2] = (unsigned short)atomicAdd(&scnt[dr], 1);
            sr = (unsigned)(s4.z - rlo);
            if (sr < RS) atomicAdd(&sdeg[sr], w4.z);
            dr = (unsigned)(d4.w - rlo);
            if (dr < RS) rank[e + 3] = (unsigned short)atomicAdd(&scnt[dr], 1);
            sr = (unsigned)(s4.w - rlo);
            if (sr < RS) atomicAdd(&sdeg[sr], w4.w);
        }
        __syncthreads();
        size_t ob = (size_t)c * NN + rlo;
        for (int i = threadIdx.x; i < RS; i += 256) {
            counts[ob + i] = scnt[i];
            degp[ob + i]   = sdeg[i];
        }
    } else {
        // ---- xh = x @ Wp^T + bp (bf16 MFMA, 16x16x32) + his = x copy ----
        int bb = b - KCB;
        const unsigned short* Pp = Pall;   // slot 0
        int wave = threadIdx.x >> 6, l = threadIdx.x & 63;
        int n0 = bb * 64 + wave * 16;
        int m = l & 15, q = l >> 4;
        int nodeA = n0 + m;
        bool av = nodeA < NN;
        int na = av ? nodeA : 0;
        floatx4 acc[8];
#pragma unroll
        for (int ct = 0; ct < 8; ++ct) acc[ct] = (floatx4)(0.f);
#pragma unroll
        for (int kc = 0; kc < 4; ++kc) {
            const float* ap = x + (size_t)na * 128 + kc * 32 + q * 8;
            float4 f0 = av ? *(const float4*)ap       : make_float4(0, 0, 0, 0);
            float4 f1 = av ? *(const float4*)(ap + 4) : make_float4(0, 0, 0, 0);
            if (av) {
                float* hp = his + (size_t)nodeA * 128 + kc * 32 + q * 8;
                *(float4*)hp       = f0;
                *(float4*)(hp + 4) = f1;
            }
            short8 a;
            a[0] = f2bf(f0.x); a[1] = f2bf(f0.y); a[2] = f2bf(f0.z); a[3] = f2bf(f0.w);
            a[4] = f2bf(f1.x); a[5] = f2bf(f1.y); a[6] = f2bf(f1.z); a[7] = f2bf(f1.w);
#pragma unroll
            for (int ct = 0; ct < 8; ++ct) {
                short8 bfr = *(const short8*)(Pp + ((kc * 8 + ct) << 9) + l * 8);
                acc[ct] = __builtin_amdgcn_mfma_f32_16x16x32_bf16(a, bfr, acc[ct], 0, 0, 0);
            }
        }
#pragma unroll
        for (int ct = 0; ct < 8; ++ct) {
            int col = ct * 16 + m;
            float bias = bp[col];
#pragma unroll
            for (int r = 0; r < 4; ++r) {
                int node = n0 + q * 4 + r;
                if (node < NN) xh16[(size_t)node * 128 + col] = f2bf(acc[ct][r] + bias);
            }
        }
    }
}

// ------------- per-node scan over chunks: chunkoff (in-place), cntI total, deg sum, blocksum -------------
__global__ __launch_bounds__(256) void k_colscan(int* __restrict__ counts,
                                                 const float* __restrict__ degp,
                                                 int* __restrict__ cntI,
                                                 float* __restrict__ deg,
                                                 int* __restrict__ blocksum) {
    __shared__ int ws4[4];
    int t = threadIdx.x;
    int n = blockIdx.x * 256 + t;
    int acc = 0; float dacc = 0.f;
    if (n < NN) {
#pragma unroll 8
        for (int c = 0; c < NCH; ++c) {
            size_t idx = (size_t)c * NN + n;
            int v = counts[idx];
            counts[idx] = acc;      // exclusive prefix over chunks (chunkoff)
            acc += v;
            dacc += degp[idx];
        }
        cntI[n] = acc;
        deg[n] = dacc;
    }
    int s = (n < NN) ? acc : 0;
#pragma unroll
    for (int off = 32; off > 0; off >>= 1) s += __shfl_down(s, off, 64);
    if ((t & 63) == 0) ws4[t >> 6] = s;
    __syncthreads();
    if (t == 0) blocksum[blockIdx.x] = ws4[0] + ws4[1] + ws4[2] + ws4[3];
}

__global__ __launch_bounds__(256) void k_scan_mid(const int* __restrict__ blocksum,
                                                  int* __restrict__ blockoff,
                                                  int* __restrict__ rowstart) {
    __shared__ int wtot[4];
    int t = threadIdx.x, lane = t & 63, wave = t >> 6;
    int v = (t < CSB) ? blocksum[t] : 0;
    int incl = v;
#pragma unroll
    for (int off = 1; off < 64; off <<= 1) {
        int u = __shfl_up(incl, off, 64);
        if (lane >= off) incl += u;
    }
    if (lane == 63) wtot[wave] = incl;
    __syncthreads();
    int wpre = 0;
    for (int w = 0; w < wave; ++w) wpre += wtot[w];
    incl += wpre;
    if (t < CSB) blockoff[t] = incl - v;
    if (t == 255) rowstart[NN] = incl;
}

__global__ __launch_bounds__(256) void k_scan_final(const int* __restrict__ cntI,
                                                    const int* __restrict__ blockoff,
                                                    int* __restrict__ rowstart) {
    __shared__ int wtot[4];
    int t = threadIdx.x, lane = t & 63, wave = t >> 6;
    int n = blockIdx.x * 256 + t;
    int v = (n < NN) ? cntI[n] : 0;
    int incl = v;
#pragma unroll
    for (int off = 1; off < 64; off <<= 1) {
        int u = __shfl_up(incl, off, 64);
        if (lane >= off) incl += u;
    }
    if (lane == 63) wtot[wave] = incl;
    __syncthreads();
    int wpre = 0;
    for (int w = 0; w < wave; ++w) wpre += wtot[w];
    incl += wpre;
    if (n < NN) rowstart[n] = blockoff[blockIdx.x] + incl - v;
}

// ------------- bucket edges by dst, NO atomics: rec[pos] = {src, w, dis_s*w, 0} -------------
__global__ __launch_bounds__(256) void k_bucket(const int* __restrict__ src,
                                                const int* __restrict__ dst,
                                                const float* __restrict__ ew,
                                                const float* __restrict__ deg,
                                                const int* __restrict__ rowstart,
                                                const int* __restrict__ chunkoff,
                                                const unsigned short* __restrict__ rank,
                                                int4* __restrict__ rec) {
    int e = blockIdx.x * blockDim.x + threadIdx.x;
    if (e >= EE) return;
    int s = src[e], d = dst[e];
    float w = ew[e];
    float degs = deg[s];
    float dis_s = degs > 0.f ? rsqrtf(degs) : 0.f;
    int c = e / CH;
    int pos = rowstart[d] + chunkoff[(size_t)c * NN + d] + (int)rank[e];
    int4 r;
    r.x = s;
    r.y = __float_as_int(w);
    r.z = __float_as_int(dis_s * w);
    r.w = 0;
    rec[pos] = r;
}

// ------------- per-dst gather on bf16 xh: Tx1, mean → bf16 -------------
// v2: 8B/lane row reads (32 lanes/row); wave halves process even/odd edges in
// parallel; shfl_xor(32) combines; half 0 writes tx, half 1 writes mn.
__global__ __launch_bounds__(256) void k_gather(const int* __restrict__ rowstart,
                                                const int4* __restrict__ rec,
                                                const float* __restrict__ deg,
                                                const unsigned short* __restrict__ xh16,
                                                unsigned int* __restrict__ tx16,
                                                unsigned int* __restrict__ mn16) {
    int wave = threadIdx.x >> 6, l = threadIdx.x & 63;
    int n = blockIdx.x * 4 + wave;
    if (n >= NN) return;
    int lo = rowstart[n], hi = rowstart[n + 1];
    int half = l >> 5, c32 = l & 31;
    float am0 = 0.f, am1 = 0.f, am2 = 0.f, am3 = 0.f;
    float at0 = 0.f, at1 = 0.f, at2 = 0.f, at3 = 0.f;
    int e = lo + half;                       // this half's edge stream: e, e+2, ...
    for (; e + 6 < hi; e += 8) {             // 4 edges per half per iter (8 total)
        int4 r0 = rec[e], r1 = rec[e + 2], r2 = rec[e + 4], r3 = rec[e + 6];
        uint2 v0 = *(const uint2*)(xh16 + (size_t)r0.x * 128 + c32 * 4);
        uint2 v1 = *(const uint2*)(xh16 + (size_t)r1.x * 128 + c32 * 4);
        uint2 v2 = *(const uint2*)(xh16 + (size_t)r2.x * 128 + c32 * 4);
        uint2 v3 = *(const uint2*)(xh16 + (size_t)r3.x * 128 + c32 * 4);
        float w0 = __int_as_float(r0.y), u0 = __int_as_float(r0.z);
        float w1 = __int_as_float(r1.y), u1 = __int_as_float(r1.z);
        float w2 = __int_as_float(r2.y), u2 = __int_as_float(r2.z);
        float w3 = __int_as_float(r3.y), u3 = __int_as_float(r3.z);
        float a0, a1, a2, a3;
        a0 = bf2f(v0.x & 0xffff); a1 = bf2f(v0.x >> 16);
        a2 = bf2f(v0.y & 0xffff); a3 = bf2f(v0.y >> 16);
        am0 = fmaf(w0, a0, am0); am1 = fmaf(w0, a1, am1);
        am2 = fmaf(w0, a2, am2); am3 = fmaf(w0, a3, am3);
        at0 = fmaf(u0, a0, at0); at1 = fmaf(u0, a1, at1);
        at2 = fmaf(u0, a2, at2); at3 = fmaf(u0, a3, at3);
        a0 = bf2f(v1.x & 0xffff); a1 = bf2f(v1.x >> 16);
        a2 = bf2f(v1.y & 0xffff); a3 = bf2f(v1.y >> 16);
        am0 = fmaf(w1, a0, am0); am1 = fmaf(w1, a1, am1);
        am2 = fmaf(w1, a2, am2); am3 = fmaf(w1, a3, am3);
        at0 = fmaf(u1, a0, at0); at1 = fmaf(u1, a1, at1);
        at2 = fmaf(u1, a2, at2); at3 = fmaf(u1, a3, at3);
        a0 = bf2f(v2.x & 0xffff); a1 = bf2f(v2.x >> 16);
        a2 = bf2f(v2.y & 0xffff); a3 = bf2f(v2.y >> 16);
        am0 = fmaf(w2, a0, am0); am1 = fmaf(w2, a1, am1);
        am2 = fmaf(w2, a2, am2); am3 = fmaf(w2, a3, am3);
        at0 = fmaf(u2, a0, at0); at1 = fmaf(u2, a1, at1);
        at2 = fmaf(u2, a2, at2); at3 = fmaf(u2, a3, at3);
        a0 = bf2f(v3.x & 0xffff); a1 = bf2f(v3.x >> 16);
        a2 = bf2f(v3.y & 0xffff); a3 = bf2f(v3.y >> 16);
        am0 = fmaf(w3, a0, am0); am1 = fmaf(w3, a1, am1);
        am2 = fmaf(w3, a2, am2); am3 = fmaf(w3, a3, am3);
        at0 = fmaf(u3, a0, at0); at1 = fmaf(u3, a1, at1);
        at2 = fmaf(u3, a2, at2); at3 = fmaf(u3, a3, at3);
    }
    for (; e < hi; e += 2) {
        int4 r0 = rec[e];
        uint2 v0 = *(const uint2*)(xh16 + (size_t)r0.x * 128 + c32 * 4);
        float w0 = __int_as_float(r0.y), u0 = __int_as_float(r0.z);
        float a0 = bf2f(v0.x & 0xffff), a1 = bf2f(v0.x >> 16);
        float a2 = bf2f(v0.y & 0xffff), a3 = bf2f(v0.y >> 16);
        am0 = fmaf(w0, a0, am0); am1 = fmaf(w0, a1, am1);
        am2 = fmaf(w0, a2, am2); am3 = fmaf(w0, a3, am3);
        at0 = fmaf(u0, a0, at0); at1 = fmaf(u0, a1, at1);
        at2 = fmaf(u0, a2, at2); at3 = fmaf(u0, a3, at3);
    }
    // combine the two half-streams
    am0 += __shfl_xor(am0, 32, 64); am1 += __shfl_xor(am1, 32, 64);
    am2 += __shfl_xor(am2, 32, 64); am3 += __shfl_xor(am3, 32, 64);
    at0 += __shfl_xor(at0, 32, 64); at1 += __shfl_xor(at1, 32, 64);
    at2 += __shfl_xor(at2, 32, 64); at3 += __shfl_xor(at3, 32, 64);
    float dd = deg[n];
    float dis_d = dd > 0.f ? rsqrtf(dd) : 0.f;
    int c = hi - lo;
    float ic = 1.f / (float)(c > 0 ? c : 1);
    if (half == 0) {
        uint2 t;
        t.x = (unsigned int)f2bf(-dis_d * at0) | ((unsigned int)f2bf(-dis_d * at1) << 16);
        t.y = (unsigned int)f2bf(-dis_d * at2) | ((unsigned int)f2bf(-dis_d * at3) << 16);
        *(uint2*)(tx16 + (size_t)n * 64 + c32 * 2) = t;
    } else {
        uint2 m;
        m.x = (unsigned int)f2bf(am0 * ic) | ((unsigned int)f2bf(am1 * ic) << 16);
        m.y = (unsigned int)f2bf(am2 * ic) | ((unsigned int)f2bf(am3 * ic) << 16);
        *(uint2*)(mn16 + (size_t)n * 64 + c32 * 2) = m;
    }
}

// ------------- fused epilogue (bf16 MFMA 32x32x16): o1, o2, s, o3 -------------
// v3: block = 32 nodes; the 4 waves each own one 32-col quadrant (ct = wave id)
// for BOTH stages, meeting at a shared 8KB sS tile. Grid 1563 blocks -> ~6
// waves/SIMD (was 1.5: round-3's 14% occupancy was grid-limited). A-fragments
// loaded per-kc (no big register arrays) to keep VGPR < 128.
__global__ __launch_bounds__(256, 4) void k_fused(const unsigned short* __restrict__ xh16,
                                               const unsigned short* __restrict__ tx16,
                                               const unsigned short* __restrict__ mn16,
                                               const unsigned short* __restrict__ Pall,
                                               const float* __restrict__ bc,
                                               const float* __restrict__ brel,
                                               const float* __restrict__ bl,
                                               float* __restrict__ out) {
    const unsigned short* Pc0  = Pall + 1 * 16384;
    const unsigned short* Pc1  = Pall + 2 * 16384;
    const unsigned short* Prel = Pall + 3 * 16384;
    const unsigned short* Proot= Pall + 4 * 16384;
    const unsigned short* Pl   = Pall + 5 * 16384;
    __shared__ __align__(16) unsigned short sS[32][128];
    int ct = threadIdx.x >> 6, l = threadIdx.x & 63;   // wave id = column quadrant
    int n0 = blockIdx.x * 32;
    int row = l & 31, half = l >> 5;
    int node = n0 + row;
    bool av = node < NN;
    size_t ra = (size_t)(av ? node : 0) * 128 + half * 8;   // + kc*16
    floatx16 acc1 = (floatx16)(0.f), acc2 = (floatx16)(0.f);
#pragma unroll
    for (int kc = 0; kc < 8; ++kc) {
        short8 Axh = *(const short8*)(xh16 + ra + kc * 16);
        short8 Atx = *(const short8*)(tx16 + ra + kc * 16);
        short8 Amn = *(const short8*)(mn16 + ra + kc * 16);
        int po = ((kc * 4 + ct) << 9) + l * 8;
        short8 b0 = *(const short8*)(Pc0 + po);
        short8 b1 = *(const short8*)(Pc1 + po);
        short8 b2 = *(const short8*)(Prel + po);
        short8 b3 = *(const short8*)(Proot + po);
        acc1 = __builtin_amdgcn_mfma_f32_32x32x16_bf16(Axh, b0, acc1, 0, 0, 0);
        acc1 = __builtin_amdgcn_mfma_f32_32x32x16_bf16(Atx, b1, acc1, 0, 0, 0);
        acc2 = __builtin_amdgcn_mfma_f32_32x32x16_bf16(Amn, b2, acc2, 0, 0, 0);
        acc2 = __builtin_amdgcn_mfma_f32_32x32x16_bf16(Axh, b3, acc2, 0, 0, 0);
    }
    int col = ct * 32 + row;
    float b1v = bc[col], b2v = brel[col];
#pragma unroll
    for (int r = 0; r < 16; ++r) {
        int rr = (r & 3) + 8 * (r >> 2) + 4 * half;     // C/D row map (m74/m101)
        float u = leaky(acc1[r] + b1v) + leaky(acc2[r] + b2v);
        int sw = ((((col >> 3) ^ rr) & 15) << 3) | (col & 7);
        sS[rr][sw] = f2bf(u);
    }
    __syncthreads();
    // stage 2: o3 = s @ Wl^T + bl  (A = sS rows via swizzled b128 reads)
    floatx16 acc3 = (floatx16)(0.f);
#pragma unroll
    for (int kc = 0; kc < 8; ++kc) {
        int g = (kc * 2 + half) ^ (row & 15);
        short8 As = *(const short8*)&sS[row][g << 3];
        short8 b = *(const short8*)(Pl + ((kc * 4 + ct) << 9) + l * 8);
        acc3 = __builtin_amdgcn_mfma_f32_32x32x16_bf16(As, b, acc3, 0, 0, 0);
    }
    float bv = bl[col];
#pragma unroll
    for (int r = 0; r < 16; ++r) {
        int rr = (r & 3) + 8 * (r >> 2) + 4 * half;
        int nd = n0 + rr;
        if (nd < NN) out[(size_t)nd * 128 + col] = acc3[r] + bv;
    }
}

extern "C" void kernel_launch(void* const* d_in, const int* in_sizes, int n_in,
                              void* d_out, int out_size, void* d_ws, size_t ws_size,
                              hipStream_t stream) {
    const float* x    = (const float*)d_in[1];
    const int*   ei   = (const int*)d_in[2];
    const float* ew   = (const float*)d_in[3];
    const float* Wp   = (const float*)d_in[4];
    const float* bp   = (const float*)d_in[5];
    const float* Wc0  = (const float*)d_in[6];
    const float* Wc1  = (const float*)d_in[7];
    const float* bc   = (const float*)d_in[8];
    const float* Wrel = (const float*)d_in[9];
    const float* brel = (const float*)d_in[10];
    const float* Wroot= (const float*)d_in[11];
    const float* Wl   = (const float*)d_in[12];
    const float* bl   = (const float*)d_in[13];
    (void)in_sizes; (void)n_in; (void)out_size; (void)ws_size;
    float* out = (float*)d_out;

    unsigned short* xh16 = (unsigned short*)d_ws;        // NN*128 bf16
    unsigned short* tx16 = xh16 + (size_t)NN * 128;
    unsigned short* mn16 = tx16 + (size_t)NN * 128;
    unsigned short* Pall = mn16 + (size_t)NN * 128;      // 6*16384 bf16
    int*   counts = (int*)(Pall + 6 * 16384);            // [NCH][NN] -> chunkoff (in-place)
    int4*  rec    = (int4*)(counts + (size_t)NCH * NN);  // EE int4; degp aliases (dead before rec written)
    float* degp   = (float*)rec;                         // [NCH][NN] floats == EE*16 bytes
    unsigned short* rank = (unsigned short*)(rec + EE);  // EE ushort (lrank < CH=12500)
    int*   rowstart = (int*)(rank + EE);                 // NN+1
    int*   blocksum = rowstart + NN + 2;                 // CSB
    int*   blockoff = blocksum + CSB;                    // CSB
    int*   cntI   = blockoff + CSB;                      // NN
    float* deg    = (float*)(cntI + NN);                 // NN

    const int* srcI = ei;
    const int* dstI = ei + EE;

    // phase A: pack weights (must complete before k_main's xh path reads Pall)
    k_pre<<<PKB, 256, 0, stream>>>(Wp, Wc0, Wc1, Wrel, Wroot, Wl, Pall);
    // phase B: LDS counting sort prep (no global atomics) ∥ xh+his (MFMA/BW)
    k_main<<<KCB + XHB, 256, 0, stream>>>(
        srcI, dstI, ew, counts, degp, rank, x, bp, xh16, out, Pall);
    k_colscan<<<CSB, 256, 0, stream>>>(counts, degp, cntI, deg, blocksum);
    k_scan_mid<<<1, 256, 0, stream>>>(blocksum, blockoff, rowstart);
    k_scan_final<<<CSB, 256, 0, stream>>>(cntI, blockoff, rowstart);
    k_bucket<<<(EE + 255) / 256, 256, 0, stream>>>(srcI, dstI, ew, deg, rowstart,
                                                   counts, rank, rec);
    k_gather<<<(NN + 3) / 4, 256, 0, stream>>>(rowstart, rec, deg, xh16,
                                               (unsigned int*)tx16, (unsigned int*)mn16);
    k_fused<<<FB, 256, 0, stream>>>(xh16, tx16, mn16, Pall,
                                    bc, brel, bl, out + (size_t)NN * 128);
}

// Round 5
// 246.063 us; speedup vs baseline: 1.3065x; 1.0464x over previous
//
#include <hip/hip_runtime.h>

#define NN 50000
#define EE 800000
#define D  128
#define NCH 64         // edge chunks
#define CH  12500      // EE/NCH
#define NR  8          // dst/src ranges
#define RS  6250       // NN/NR
#define KCB 512        // dst-count blocks (type A)
#define KCB2 1024      // + src-degree blocks (type B)
#define XHB 782        // xh blocks: ceil(NN/64)
#define CSB 196        // colscan/scan blocks: ceil(NN/256)
#define PKB 384        // pack blocks: 6*16384/256
#define FB  1563       // fused blocks: ceil(NN/32); 4 waves split the 4 col-quadrants

typedef short short8 __attribute__((ext_vector_type(8)));
typedef float floatx4 __attribute__((ext_vector_type(4)));
typedef float floatx16 __attribute__((ext_vector_type(16)));

__device__ __forceinline__ float leaky(float v) { return v > 0.f ? v : 0.01f * v; }

__device__ __forceinline__ unsigned short f2bf(float f) {
    unsigned int u = __float_as_uint(f);
    u = (u + 0x7fff + ((u >> 16) & 1)) >> 16;     // round-to-nearest-even
    return (unsigned short)u;
}
__device__ __forceinline__ float bf2f(unsigned int h) {
    return __uint_as_float(h << 16);
}

// ------------- phase A: pack weights to bf16 MFMA layouts -------------
// slot 0 (Wp): 16x16x32 layout (k_main's xh GEMM)
// slots 1-5:   32x32x16 layout (k_fused)
__global__ __launch_bounds__(256) void k_pre(
    const float* __restrict__ Wp,  const float* __restrict__ Wc0,
    const float* __restrict__ Wc1, const float* __restrict__ Wrel,
    const float* __restrict__ Wroot, const float* __restrict__ Wl,
    unsigned short* __restrict__ Pall) {
    int gid = blockIdx.x * 256 + threadIdx.x;
    int mm = gid >> 14;
    int r = gid & 16383;
    int j  = r & 7;
    int l  = (r >> 3) & 63;
    int n, k;
    if (mm == 0) {                  // 16x16x32: frag (kc,ct), n=ct*16+(l&15), k=kc*32+(l>>4)*8+j
        int ct = (r >> 9) & 7;
        int kc = r >> 12;
        n = ct * 16 + (l & 15);
        k = kc * 32 + (l >> 4) * 8 + j;
    } else {                        // 32x32x16: frag (kc,ct), n=ct*32+(l&31), k=kc*16+(l>>5)*8+j
        int ct = (r >> 9) & 3;
        int kc = (r >> 11) & 7;
        n = ct * 32 + (l & 31);
        k = kc * 16 + (l >> 5) * 8 + j;
    }
    const float* W = mm == 0 ? Wp : mm == 1 ? Wc0 : mm == 2 ? Wc1
                   : mm == 3 ? Wrel : mm == 4 ? Wroot : Wl;
    Pall[gid] = f2bf(W[n * 128 + k]);
}

// ------------- phase B: LDS-privatized count (A) / degsum (B) / xh+his (C) -------------
// 25KB union LDS buffer -> 6 blocks/CU (round-4's 50KB gave 3: occupancy-starved).
// Type A packs 2 ushort counters per int (per-(chunk,dst) count <= 12500 < 2^16,
// so +1<<16 on the high half can't carry out and halves stay independent).
__global__ __launch_bounds__(256) void k_main(
    const int* __restrict__ src, const int* __restrict__ dst,
    const float* __restrict__ ew,
    int* __restrict__ counts,            // [NCH][NN] per-chunk dst counts
    float* __restrict__ degp,            // [NCH][NN] per-chunk src weighted-degree partials
    unsigned short* __restrict__ rank,   // [EE] within-(chunk,dst) rank
    const float* __restrict__ x, const float* __restrict__ bp,
    unsigned short* __restrict__ xh16, float* __restrict__ his,
    const unsigned short* __restrict__ Pall) {
    __shared__ __align__(16) unsigned int sbuf[6272];   // 25.1 KB union
    int b = blockIdx.x;
    if (b < KCB) {
        // ---- type A: dst counting, packed ushort counters (12.5 KB used) ----
        // c = b&63 keeps all blocks of chunk c on XCD c%8 (chunk stays in one L2).
        int c = b & 63;
        int rlo = (b >> 6) * RS;
        for (int i = threadIdx.x; i < RS / 2; i += 256) sbuf[i] = 0u;
        __syncthreads();
        int base = c * CH;
        for (int i0 = threadIdx.x * 4; i0 < CH; i0 += 1024) {
            int e = base + i0;
            int4 d4 = *(const int4*)(dst + e);
            unsigned dr;
            dr = (unsigned)(d4.x - rlo);
            if (dr < RS) {
                unsigned old = atomicAdd(&sbuf[dr >> 1], 1u << ((dr & 1) * 16));
                rank[e]     = (unsigned short)(old >> ((dr & 1) * 16));
            }
            dr = (unsigned)(d4.y - rlo);
            if (dr < RS) {
                unsigned old = atomicAdd(&sbuf[dr >> 1], 1u << ((dr & 1) * 16));
                rank[e + 1] = (unsigned short)(old >> ((dr & 1) * 16));
            }
            dr = (unsigned)(d4.z - rlo);
            if (dr < RS) {
                unsigned old = atomicAdd(&sbuf[dr >> 1], 1u << ((dr & 1) * 16));
                rank[e + 2] = (unsigned short)(old >> ((dr & 1) * 16));
            }
            dr = (unsigned)(d4.w - rlo);
            if (dr < RS) {
                unsigned old = atomicAdd(&sbuf[dr >> 1], 1u << ((dr & 1) * 16));
                rank[e + 3] = (unsigned short)(old >> ((dr & 1) * 16));
            }
        }
        __syncthreads();
        size_t ob = (size_t)c * NN + rlo;
        for (int i = threadIdx.x; i < RS; i += 256)
            counts[ob + i] = (int)((sbuf[i >> 1] >> ((i & 1) * 16)) & 0xffffu);
    } else if (b < KCB2) {
        // ---- type B: src weighted degree (25 KB floats) ----
        int bb = b - KCB;
        int c = bb & 63;                 // b%8 == c%8 still (512%8==0)
        int rlo = (bb >> 6) * RS;
        float* sdeg = (float*)sbuf;
        for (int i = threadIdx.x; i < RS; i += 256) sdeg[i] = 0.f;
        __syncthreads();
        int base = c * CH;
        for (int i0 = threadIdx.x * 4; i0 < CH; i0 += 1024) {
            int e = base + i0;
            int4   s4 = *(const int4*)(src + e);
            float4 w4 = *(const float4*)(ew + e);
            unsigned sr;
            sr = (unsigned)(s4.x - rlo); if (sr < RS) atomicAdd(&sdeg[sr], w4.x);
            sr = (unsigned)(s4.y - rlo); if (sr < RS) atomicAdd(&sdeg[sr], w4.y);
            sr = (unsigned)(s4.z - rlo); if (sr < RS) atomicAdd(&sdeg[sr], w4.z);
            sr = (unsigned)(s4.w - rlo); if (sr < RS) atomicAdd(&sdeg[sr], w4.w);
        }
        __syncthreads();
        size_t ob = (size_t)c * NN + rlo;
        for (int i = threadIdx.x; i < RS; i += 256) degp[ob + i] = sdeg[i];
    } else {
        // ---- type C: xh = x @ Wp^T + bp (bf16 MFMA, 16x16x32) + his = x copy ----
        int bb = b - KCB2;
        const unsigned short* Pp = Pall;   // slot 0
        int wave = threadIdx.x >> 6, l = threadIdx.x & 63;
        int n0 = bb * 64 + wave * 16;
        int m = l & 15, q = l >> 4;
        int nodeA = n0 + m;
        bool av = nodeA < NN;
        int na = av ? nodeA : 0;
        floatx4 acc[8];
#pragma unroll
        for (int ct = 0; ct < 8; ++ct) acc[ct] = (floatx4)(0.f);
#pragma unroll
        for (int kc = 0; kc < 4; ++kc) {
            const float* ap = x + (size_t)na * 128 + kc * 32 + q * 8;
            float4 f0 = av ? *(const float4*)ap       : make_float4(0, 0, 0, 0);
            float4 f1 = av ? *(const float4*)(ap + 4) : make_float4(0, 0, 0, 0);
            if (av) {
                float* hp = his + (size_t)nodeA * 128 + kc * 32 + q * 8;
                *(float4*)hp       = f0;
                *(float4*)(hp + 4) = f1;
            }
            short8 a;
            a[0] = f2bf(f0.x); a[1] = f2bf(f0.y); a[2] = f2bf(f0.z); a[3] = f2bf(f0.w);
            a[4] = f2bf(f1.x); a[5] = f2bf(f1.y); a[6] = f2bf(f1.z); a[7] = f2bf(f1.w);
#pragma unroll
            for (int ct = 0; ct < 8; ++ct) {
                short8 bfr = *(const short8*)(Pp + ((kc * 8 + ct) << 9) + l * 8);
                acc[ct] = __builtin_amdgcn_mfma_f32_16x16x32_bf16(a, bfr, acc[ct], 0, 0, 0);
            }
        }
#pragma unroll
        for (int ct = 0; ct < 8; ++ct) {
            int col = ct * 16 + m;
            float bias = bp[col];
#pragma unroll
            for (int r = 0; r < 4; ++r) {
                int node = n0 + q * 4 + r;
                if (node < NN) xh16[(size_t)node * 128 + col] = f2bf(acc[ct][r] + bias);
            }
        }
    }
}

// ------------- per-node scan over chunks: chunkoff (in-place), cntI total, deg sum, blocksum -------------
__global__ __launch_bounds__(256) void k_colscan(int* __restrict__ counts,
                                                 const float* __restrict__ degp,
                                                 int* __restrict__ cntI,
                                                 float* __restrict__ deg,
                                                 int* __restrict__ blocksum) {
    __shared__ int ws4[4];
    int t = threadIdx.x;
    int n = blockIdx.x * 256 + t;
    int acc = 0; float dacc = 0.f;
    if (n < NN) {
#pragma unroll 8
        for (int c = 0; c < NCH; ++c) {
            size_t idx = (size_t)c * NN + n;
            int v = counts[idx];
            counts[idx] = acc;      // exclusive prefix over chunks (chunkoff)
            acc += v;
            dacc += degp[idx];
        }
        cntI[n] = acc;
        deg[n] = dacc;
    }
    int s = (n < NN) ? acc : 0;
#pragma unroll
    for (int off = 32; off > 0; off >>= 1) s += __shfl_down(s, off, 64);
    if ((t & 63) == 0) ws4[t >> 6] = s;
    __syncthreads();
    if (t == 0) blocksum[blockIdx.x] = ws4[0] + ws4[1] + ws4[2] + ws4[3];
}

__global__ __launch_bounds__(256) void k_scan_mid(const int* __restrict__ blocksum,
                                                  int* __restrict__ blockoff,
                                                  int* __restrict__ rowstart) {
    __shared__ int wtot[4];
    int t = threadIdx.x, lane = t & 63, wave = t >> 6;
    int v = (t < CSB) ? blocksum[t] : 0;
    int incl = v;
#pragma unroll
    for (int off = 1; off < 64; off <<= 1) {
        int u = __shfl_up(incl, off, 64);
        if (lane >= off) incl += u;
    }
    if (lane == 63) wtot[wave] = incl;
    __syncthreads();
    int wpre = 0;
    for (int w = 0; w < wave; ++w) wpre += wtot[w];
    incl += wpre;
    if (t < CSB) blockoff[t] = incl - v;
    if (t == 255) rowstart[NN] = incl;
}

__global__ __launch_bounds__(256) void k_scan_final(const int* __restrict__ cntI,
                                                    const int* __restrict__ blockoff,
                                                    int* __restrict__ rowstart) {
    __shared__ int wtot[4];
    int t = threadIdx.x, lane = t & 63, wave = t >> 6;
    int n = blockIdx.x * 256 + t;
    int v = (n < NN) ? cntI[n] : 0;
    int incl = v;
#pragma unroll
    for (int off = 1; off < 64; off <<= 1) {
        int u = __shfl_up(incl, off, 64);
        if (lane >= off) incl += u;
    }
    if (lane == 63) wtot[wave] = incl;
    __syncthreads();
    int wpre = 0;
    for (int w = 0; w < wave; ++w) wpre += wtot[w];
    incl += wpre;
    if (n < NN) rowstart[n] = blockoff[blockIdx.x] + incl - v;
}

// ------------- bucket edges by dst, NO atomics: rec[pos] = {src, w, dis_s*w, 0} -------------
__global__ __launch_bounds__(256) void k_bucket(const int* __restrict__ src,
                                                const int* __restrict__ dst,
                                                const float* __restrict__ ew,
                                                const float* __restrict__ deg,
                                                const int* __restrict__ rowstart,
                                                const int* __restrict__ chunkoff,
                                                const unsigned short* __restrict__ rank,
                                                int4* __restrict__ rec) {
    int e = blockIdx.x * blockDim.x + threadIdx.x;
    if (e >= EE) return;
    int s = src[e], d = dst[e];
    float w = ew[e];
    float degs = deg[s];
    float dis_s = degs > 0.f ? rsqrtf(degs) : 0.f;
    int c = e / CH;
    int pos = rowstart[d] + chunkoff[(size_t)c * NN + d] + (int)rank[e];
    int4 r;
    r.x = s;
    r.y = __float_as_int(w);
    r.z = __float_as_int(dis_s * w);
    r.w = 0;
    rec[pos] = r;
}

// ------------- per-dst gather on bf16 xh: Tx1, mean → bf16 -------------
// 8B/lane row reads (32 lanes/row); wave halves process even/odd edges in
// parallel; shfl_xor(32) combines; half 0 writes tx, half 1 writes mn.
__global__ __launch_bounds__(256) void k_gather(const int* __restrict__ rowstart,
                                                const int4* __restrict__ rec,
                                                const float* __restrict__ deg,
                                                const unsigned short* __restrict__ xh16,
                                                unsigned int* __restrict__ tx16,
                                                unsigned int* __restrict__ mn16) {
    int wave = threadIdx.x >> 6, l = threadIdx.x & 63;
    int n = blockIdx.x * 4 + wave;
    if (n >= NN) return;
    int lo = rowstart[n], hi = rowstart[n + 1];
    int half = l >> 5, c32 = l & 31;
    float am0 = 0.f, am1 = 0.f, am2 = 0.f, am3 = 0.f;
    float at0 = 0.f, at1 = 0.f, at2 = 0.f, at3 = 0.f;
    int e = lo + half;                       // this half's edge stream: e, e+2, ...
    for (; e + 6 < hi; e += 8) {             // 4 edges per half per iter (8 total)
        int4 r0 = rec[e], r1 = rec[e + 2], r2 = rec[e + 4], r3 = rec[e + 6];
        uint2 v0 = *(const uint2*)(xh16 + (size_t)r0.x * 128 + c32 * 4);
        uint2 v1 = *(const uint2*)(xh16 + (size_t)r1.x * 128 + c32 * 4);
        uint2 v2 = *(const uint2*)(xh16 + (size_t)r2.x * 128 + c32 * 4);
        uint2 v3 = *(const uint2*)(xh16 + (size_t)r3.x * 128 + c32 * 4);
        float w0 = __int_as_float(r0.y), u0 = __int_as_float(r0.z);
        float w1 = __int_as_float(r1.y), u1 = __int_as_float(r1.z);
        float w2 = __int_as_float(r2.y), u2 = __int_as_float(r2.z);
        float w3 = __int_as_float(r3.y), u3 = __int_as_float(r3.z);
        float a0, a1, a2, a3;
        a0 = bf2f(v0.x & 0xffff); a1 = bf2f(v0.x >> 16);
        a2 = bf2f(v0.y & 0xffff); a3 = bf2f(v0.y >> 16);
        am0 = fmaf(w0, a0, am0); am1 = fmaf(w0, a1, am1);
        am2 = fmaf(w0, a2, am2); am3 = fmaf(w0, a3, am3);
        at0 = fmaf(u0, a0, at0); at1 = fmaf(u0, a1, at1);
        at2 = fmaf(u0, a2, at2); at3 = fmaf(u0, a3, at3);
        a0 = bf2f(v1.x & 0xffff); a1 = bf2f(v1.x >> 16);
        a2 = bf2f(v1.y & 0xffff); a3 = bf2f(v1.y >> 16);
        am0 = fmaf(w1, a0, am0); am1 = fmaf(w1, a1, am1);
        am2 = fmaf(w1, a2, am2); am3 = fmaf(w1, a3, am3);
        at0 = fmaf(u1, a0, at0); at1 = fmaf(u1, a1, at1);
        at2 = fmaf(u1, a2, at2); at3 = fmaf(u1, a3, at3);
        a0 = bf2f(v2.x & 0xffff); a1 = bf2f(v2.x >> 16);
        a2 = bf2f(v2.y & 0xffff); a3 = bf2f(v2.y >> 16);
        am0 = fmaf(w2, a0, am0); am1 = fmaf(w2, a1, am1);
        am2 = fmaf(w2, a2, am2); am3 = fmaf(w2, a3, am3);
        at0 = fmaf(u2, a0, at0); at1 = fmaf(u2, a1, at1);
        at2 = fmaf(u2, a2, at2); at3 = fmaf(u2, a3, at3);
        a0 = bf2f(v3.x & 0xffff); a1 = bf2f(v3.x >> 16);
        a2 = bf2f(v3.y & 0xffff); a3 = bf2f(v3.y >> 16);
        am0 = fmaf(w3, a0, am0); am1 = fmaf(w3, a1, am1);
        am2 = fmaf(w3, a2, am2); am3 = fmaf(w3, a3, am3);
        at0 = fmaf(u3, a0, at0); at1 = fmaf(u3, a1, at1);
        at2 = fmaf(u3, a2, at2); at3 = fmaf(u3, a3, at3);
    }
    for (; e < hi; e += 2) {
        int4 r0 = rec[e];
        uint2 v0 = *(const uint2*)(xh16 + (size_t)r0.x * 128 + c32 * 4);
        float w0 = __int_as_float(r0.y), u0 = __int_as_float(r0.z);
        float a0 = bf2f(v0.x & 0xffff), a1 = bf2f(v0.x >> 16);
        float a2 = bf2f(v0.y & 0xffff), a3 = bf2f(v0.y >> 16);
        am0 = fmaf(w0, a0, am0); am1 = fmaf(w0, a1, am1);
        am2 = fmaf(w0, a2, am2); am3 = fmaf(w0, a3, am3);
        at0 = fmaf(u0, a0, at0); at1 = fmaf(u0, a1, at1);
        at2 = fmaf(u0, a2, at2); at3 = fmaf(u0, a3, at3);
    }
    // combine the two half-streams
    am0 += __shfl_xor(am0, 32, 64); am1 += __shfl_xor(am1, 32, 64);
    am2 += __shfl_xor(am2, 32, 64); am3 += __shfl_xor(am3, 32, 64);
    at0 += __shfl_xor(at0, 32, 64); at1 += __shfl_xor(at1, 32, 64);
    at2 += __shfl_xor(at2, 32, 64); at3 += __shfl_xor(at3, 32, 64);
    float dd = deg[n];
    float dis_d = dd > 0.f ? rsqrtf(dd) : 0.f;
    int c = hi - lo;
    float ic = 1.f / (float)(c > 0 ? c : 1);
    if (half == 0) {
        uint2 t;
        t.x = (unsigned int)f2bf(-dis_d * at0) | ((unsigned int)f2bf(-dis_d * at1) << 16);
        t.y = (unsigned int)f2bf(-dis_d * at2) | ((unsigned int)f2bf(-dis_d * at3) << 16);
        *(uint2*)(tx16 + (size_t)n * 64 + c32 * 2) = t;
    } else {
        uint2 m;
        m.x = (unsigned int)f2bf(am0 * ic) | ((unsigned int)f2bf(am1 * ic) << 16);
        m.y = (unsigned int)f2bf(am2 * ic) | ((unsigned int)f2bf(am3 * ic) << 16);
        *(uint2*)(mn16 + (size_t)n * 64 + c32 * 2) = m;
    }
}

// ------------- fused epilogue (bf16 MFMA 32x32x16): o1, o2, s, o3 -------------
// block = 32 nodes; the 4 waves each own one 32-col quadrant (ct = wave id)
// for BOTH stages, meeting at a shared 8KB sS tile.
__global__ __launch_bounds__(256, 4) void k_fused(const unsigned short* __restrict__ xh16,
                                               const unsigned short* __restrict__ tx16,
                                               const unsigned short* __restrict__ mn16,
                                               const unsigned short* __restrict__ Pall,
                                               const float* __restrict__ bc,
                                               const float* __restrict__ brel,
                                               const float* __restrict__ bl,
                                               float* __restrict__ out) {
    const unsigned short* Pc0  = Pall + 1 * 16384;
    const unsigned short* Pc1  = Pall + 2 * 16384;
    const unsigned short* Prel = Pall + 3 * 16384;
    const unsigned short* Proot= Pall + 4 * 16384;
    const unsigned short* Pl   = Pall + 5 * 16384;
    __shared__ __align__(16) unsigned short sS[32][128];
    int ct = threadIdx.x >> 6, l = threadIdx.x & 63;   // wave id = column quadrant
    int n0 = blockIdx.x * 32;
    int row = l & 31, half = l >> 5;
    int node = n0 + row;
    bool av = node < NN;
    size_t ra = (size_t)(av ? node : 0) * 128 + half * 8;   // + kc*16
    floatx16 acc1 = (floatx16)(0.f), acc2 = (floatx16)(0.f);
#pragma unroll
    for (int kc = 0; kc < 8; ++kc) {
        short8 Axh = *(const short8*)(xh16 + ra + kc * 16);
        short8 Atx = *(const short8*)(tx16 + ra + kc * 16);
        short8 Amn = *(const short8*)(mn16 + ra + kc * 16);
        int po = ((kc * 4 + ct) << 9) + l * 8;
        short8 b0 = *(const short8*)(Pc0 + po);
        short8 b1 = *(const short8*)(Pc1 + po);
        short8 b2 = *(const short8*)(Prel + po);
        short8 b3 = *(const short8*)(Proot + po);
        acc1 = __builtin_amdgcn_mfma_f32_32x32x16_bf16(Axh, b0, acc1, 0, 0, 0);
        acc1 = __builtin_amdgcn_mfma_f32_32x32x16_bf16(Atx, b1, acc1, 0, 0, 0);
        acc2 = __builtin_amdgcn_mfma_f32_32x32x16_bf16(Amn, b2, acc2, 0, 0, 0);
        acc2 = __builtin_amdgcn_mfma_f32_32x32x16_bf16(Axh, b3, acc2, 0, 0, 0);
    }
    int col = ct * 32 + row;
    float b1v = bc[col], b2v = brel[col];
#pragma unroll
    for (int r = 0; r < 16; ++r) {
        int rr = (r & 3) + 8 * (r >> 2) + 4 * half;     // C/D row map (m74/m101)
        float u = leaky(acc1[r] + b1v) + leaky(acc2[r] + b2v);
        int sw = ((((col >> 3) ^ rr) & 15) << 3) | (col & 7);
        sS[rr][sw] = f2bf(u);
    }
    __syncthreads();
    // stage 2: o3 = s @ Wl^T + bl  (A = sS rows via swizzled b128 reads)
    floatx16 acc3 = (floatx16)(0.f);
#pragma unroll
    for (int kc = 0; kc < 8; ++kc) {
        int g = (kc * 2 + half) ^ (row & 15);
        short8 As = *(const short8*)&sS[row][g << 3];
        short8 b = *(const short8*)(Pl + ((kc * 4 + ct) << 9) + l * 8);
        acc3 = __builtin_amdgcn_mfma_f32_32x32x16_bf16(As, b, acc3, 0, 0, 0);
    }
    float bv = bl[col];
#pragma unroll
    for (int r = 0; r < 16; ++r) {
        int rr = (r & 3) + 8 * (r >> 2) + 4 * half;
        int nd = n0 + rr;
        if (nd < NN) out[(size_t)nd * 128 + col] = acc3[r] + bv;
    }
}

extern "C" void kernel_launch(void* const* d_in, const int* in_sizes, int n_in,
                              void* d_out, int out_size, void* d_ws, size_t ws_size,
                              hipStream_t stream) {
    const float* x    = (const float*)d_in[1];
    const int*   ei   = (const int*)d_in[2];
    const float* ew   = (const float*)d_in[3];
    const float* Wp   = (const float*)d_in[4];
    const float* bp   = (const float*)d_in[5];
    const float* Wc0  = (const float*)d_in[6];
    const float* Wc1  = (const float*)d_in[7];
    const float* bc   = (const float*)d_in[8];
    const float* Wrel = (const float*)d_in[9];
    const float* brel = (const float*)d_in[10];
    const float* Wroot= (const float*)d_in[11];
    const float* Wl   = (const float*)d_in[12];
    const float* bl   = (const float*)d_in[13];
    (void)in_sizes; (void)n_in; (void)out_size; (void)ws_size;
    float* out = (float*)d_out;

    unsigned short* xh16 = (unsigned short*)d_ws;        // NN*128 bf16
    unsigned short* tx16 = xh16 + (size_t)NN * 128;
    unsigned short* mn16 = tx16 + (size_t)NN * 128;
    unsigned short* Pall = mn16 + (size_t)NN * 128;      // 6*16384 bf16
    int*   counts = (int*)(Pall + 6 * 16384);            // [NCH][NN] -> chunkoff (in-place)
    int4*  rec    = (int4*)(counts + (size_t)NCH * NN);  // EE int4; degp aliases (dead before rec written)
    float* degp   = (float*)rec;                         // [NCH][NN] floats == EE*16 bytes
    unsigned short* rank = (unsigned short*)(rec + EE);  // EE ushort (lrank < CH=12500)
    int*   rowstart = (int*)(rank + EE);                 // NN+1
    int*   blocksum = rowstart + NN + 2;                 // CSB
    int*   blockoff = blocksum + CSB;                    // CSB
    int*   cntI   = blockoff + CSB;                      // NN
    float* deg    = (float*)(cntI + NN);                 // NN

    const int* srcI = ei;
    const int* dstI = ei + EE;

    // phase A: pack weights (must complete before k_main's xh path reads Pall)
    k_pre<<<PKB, 256, 0, stream>>>(Wp, Wc0, Wc1, Wrel, Wroot, Wl, Pall);
    // phase B: LDS counting sort prep (no global atomics) ∥ xh+his (MFMA/BW)
    k_main<<<KCB2 + XHB, 256, 0, stream>>>(
        srcI, dstI, ew, counts, degp, rank, x, bp, xh16, out, Pall);
    k_colscan<<<CSB, 256, 0, stream>>>(counts, degp, cntI, deg, blocksum);
    k_scan_mid<<<1, 256, 0, stream>>>(blocksum, blockoff, rowstart);
    k_scan_final<<<CSB, 256, 0, stream>>>(cntI, blockoff, rowstart);
    k_bucket<<<(EE + 255) / 256, 256, 0, stream>>>(srcI, dstI, ew, deg, rowstart,
                                                   counts, rank, rec);
    k_gather<<<(NN + 3) / 4, 256, 0, stream>>>(rowstart, rec, deg, xh16,
                                               (unsigned int*)tx16, (unsigned int*)mn16);
    k_fused<<<FB, 256, 0, stream>>>(xh16, tx16, mn16, Pall,
                                    bc, brel, bl, out + (size_t)NN * 128);
}